// Round 8
// baseline (1372.250 us; speedup 1.0000x reference)
//
#include <hip/hip_runtime.h>
#include <math.h>

// ---------------------------------------------------------------------------
// CrossGroupedQueryAttention on MI355X — round 8
//
// R7 post-mortem: counted-vmcnt depth-2 = NEUTRAL (compiler re-inserts
// conservative waits; lever abandoned). Real signal: all 3 GEMM dispatches
// run at the SAME ~1.8 TB/s effective HBM bw (q 301MB/165us, kv 250/165,
// out 287/170) -> limiter is DRAM burst efficiency of 256B-segment reads /
// 128B-segment writes at 64KB stride, not scheduling. Fix is geometric:
// 256-px tile (128o x 256p, 8 waves, acc[4][4]), float4 B loads (1KB
// contiguous per instr), 512B+ write segments, 16 MFMA/wave/step.
// Plain dbuf + syncthreads (compiler schedules fine-grained waits itself).
// ---------------------------------------------------------------------------

typedef unsigned short u16;
typedef unsigned int u32;
typedef short s16x8 __attribute__((ext_vector_type(8)));
typedef float f32x4 __attribute__((ext_vector_type(4)));

#define HW 16384
#define NB 8
#define CDIM 384
#define KVC 192

__device__ __forceinline__ float b2f(u16 u) {
  return __uint_as_float(((u32)u) << 16);
}
__device__ __forceinline__ u16 f2b(float f) {
  u32 u = __float_as_uint(f);
  u += 0x7fffu + ((u >> 16) & 1u);   // RNE
  return (u16)(u >> 16);
}
__device__ __forceinline__ int swz(int r) {          // LDS chunk swizzle
  return (r & 3) ^ ((r >> 2) & 3) ^ ((r >> 4) & 3);
}
__device__ __forceinline__ void gll16(const void* g, void* l) {
  __builtin_amdgcn_global_load_lds(
      (const __attribute__((address_space(1))) u32*)g,
      (__attribute__((address_space(3))) u32*)l, 16, 0, 0);
}

// ---------------------------------------------------------------------------
// k0: fold LN weights into conv weights.  1024 threads.
// ---------------------------------------------------------------------------
__global__ void k0_prep(const float* __restrict__ wq, const float* __restrict__ wkv,
                        const float* __restrict__ wo,
                        const float* __restrict__ lnqw, const float* __restrict__ lnqb,
                        const float* __restrict__ lnkw, const float* __restrict__ lnkb,
                        u16* __restrict__ wqp, float* __restrict__ rwsQ, float* __restrict__ biasQ,
                        u16* __restrict__ wkvp, float* __restrict__ rwsKV, float* __restrict__ biasKV,
                        u16* __restrict__ wop) {
  int r = blockIdx.x * 256 + threadIdx.x;
  if (r < 384) {
    float rs = 0.f, bs = 0.f;
    for (int i = 0; i < 384; ++i) {
      float wp = wq[r * 384 + i] * lnqw[i];
      u16 h = f2b(wp);
      rs += b2f(h);
      bs += wq[r * 384 + i] * lnqb[i];
      wqp[r * 384 + i] = h;
    }
    rwsQ[r] = rs; biasQ[r] = bs;
  } else if (r < 640) {
    int o = r - 384;
    if (o < 192) {
      float rs = 0.f, bs = 0.f;
      for (int i = 0; i < 384; ++i) {
        float wp = wkv[o * 384 + i] * lnkw[i];
        u16 h = f2b(wp);
        rs += b2f(h);
        bs += wkv[o * 384 + i] * lnkb[i];
        wkvp[o * 384 + i] = h;
      }
      rwsKV[o] = rs; biasKV[o] = bs;
    } else {
      for (int i = 0; i < 384; ++i) wkvp[o * 384 + i] = 0;
      rwsKV[o] = 0.f; biasKV[o] = 0.f;
    }
  } else {
    int o = r - 640;
    for (int i = 0; i < 384; ++i) wop[o * 384 + i] = f2b(wo[o * 384 + i]);
  }
}

// ---------------------------------------------------------------------------
// gemm_fused: D[o][p] = sum_k A[o][k]*B[p][k], K=384, tile 128o x 256p,
// 512 thr (8 waves 2m x 4n), wave-tile 64x64, acc[4][4].
// A: 8KB/step via gll16 (1 instr/thread, pre-swizzled source, XOR on read).
// MODE 0: B from f32 NCHW via float4 (lane=4px -> 1KB/instr, 4 ch/thread),
//         cvt+LN-stats in regs, ds_write_b64 into stride-36 padded tile;
//         LN epilogue; bf16 out [b][M][hw].
// MODE 1: B (yt bf16 [p][384]) via gll16 x2 (pre-swizzled); f32 NCHW out.
// ---------------------------------------------------------------------------
template <int MODE>
__global__ __launch_bounds__(512, 4) void gemm_fused(const u16* __restrict__ A,
                                                     const void* __restrict__ Bsrc,
                                                     const float* __restrict__ rowsum,
                                                     const float* __restrict__ bias,
                                                     void* __restrict__ outv, int M) {
  __shared__ u16 tA[2][128 * 32];
  __shared__ u16 tB[2][MODE == 0 ? 256 * 36 : 256 * 32];
  __shared__ float sredS[MODE == 0 ? 8 : 1][MODE == 0 ? 256 : 1];
  __shared__ float sredQ[MODE == 0 ? 8 : 1][MODE == 0 ? 256 : 1];
  __shared__ float muL[MODE == 0 ? 256 : 1], sdL[MODE == 0 ? 256 : 1];

  const int b = blockIdx.z, ot = blockIdx.y, pt = blockIdx.x;
  const int tid = threadIdx.x;
  const int w = tid >> 6, l = tid & 63;
  const int wm = w >> 2, wn = w & 3, lr = l & 15, lg = l >> 4;

  f32x4 acc[4][4] = {};

  // ---- A gll mapping: chunk = tid -> row tid>>2, c4 = tid&3 (pre-swizzled src)
  const int rA = tid >> 2, cA = tid & 3;
  const u16* aS = A + (size_t)(ot * 128 + rA) * 384 + (cA ^ swz(rA)) * 8;
  u16* aDst0 = &tA[0][w * 512];       // wave-uniform; lane auto-offset l*16B
  u16* aDst1 = &tA[1][w * 512];

  // ---- B staging
  const float* Bf = (const float*)Bsrc;
  const u16* Bh = (const u16*)Bsrc;
  // MODE 0: lane l -> px quad 4l..4l+3; wave w + j -> channel w*4+j
  const size_t fbase = (size_t)b * CDIM * HW + (size_t)pt * 256 + 4 * l;
  // MODE 1: two gll instrs: rows tid>>2 and 128+(tid>>2)
  const int rB = tid >> 2;
  const u16* bS0 = Bh + ((size_t)(b * HW + pt * 256 + rB)) * 384 + ((tid & 3) ^ swz(rB)) * 8;
  const u16* bS1 = Bh + ((size_t)(b * HW + pt * 256 + 128 + rB)) * 384 + ((tid & 3) ^ swz(128 + rB)) * 8;

  float4 pv[4];
  float sum4[4] = {0.f, 0.f, 0.f, 0.f}, sq4[4] = {0.f, 0.f, 0.f, 0.f};

  auto stageA = [&](int ks, int buf) {
    gll16(aS + ks * 32, buf ? aDst1 : aDst0);
  };
  auto stageB1 = [&](int ks, int buf) {
    gll16(bS0 + ks * 32, &tB[buf][w * 512]);
    gll16(bS1 + ks * 32, &tB[buf][4096 + w * 512]);
  };
  auto loadB0 = [&](int ks) {
#pragma unroll
    for (int j = 0; j < 4; ++j)
      pv[j] = *(const float4*)(Bf + fbase + (size_t)(ks * 32 + w * 4 + j) * HW);
  };
  auto storeB0 = [&](int buf) {
#pragma unroll
    for (int i = 0; i < 4; ++i) {
      float v0 = pv[0][i], v1 = pv[1][i], v2 = pv[2][i], v3 = pv[3][i];
      sum4[i] += (v0 + v1) + (v2 + v3);
      sq4[i] += (v0 * v0 + v1 * v1) + (v2 * v2 + v3 * v3);
      u32 lo = (u32)f2b(v0) | ((u32)f2b(v1) << 16);
      u32 hi = (u32)f2b(v2) | ((u32)f2b(v3) << 16);
      *(uint2*)&tB[buf][(4 * l + i) * 36 + w * 4] = make_uint2(lo, hi);
    }
  };

  // ---- prologue
  if (MODE == 0) { loadB0(0); stageA(0, 0); storeB0(0); }
  else { stageB1(0, 0); stageA(0, 0); }
  __syncthreads();

  int cur = 0;
#pragma unroll
  for (int ks = 0; ks < 12; ++ks) {
    const int nxt = cur ^ 1;
    if (ks < 11) {
      if (MODE == 0) loadB0(ks + 1);
      stageA(ks + 1, nxt);
      if (MODE == 1) stageB1(ks + 1, nxt);
    }

    // ---- fragments from buf cur
    s16x8 a[4], bb[4];
#pragma unroll
    for (int mf = 0; mf < 4; ++mf) {
      int row = wm * 64 + mf * 16 + lr;
      a[mf] = *(const s16x8*)&tA[cur][row * 32 + (lg ^ swz(row)) * 8];
    }
#pragma unroll
    for (int nf = 0; nf < 4; ++nf) {
      int row = wn * 64 + nf * 16 + lr;
      if (MODE == 0) bb[nf] = *(const s16x8*)&tB[cur][row * 36 + lg * 8];
      else           bb[nf] = *(const s16x8*)&tB[cur][row * 32 + (lg ^ swz(row)) * 8];
    }
#pragma unroll
    for (int mf = 0; mf < 4; ++mf)
#pragma unroll
      for (int nf = 0; nf < 4; ++nf)
        acc[mf][nf] = __builtin_amdgcn_mfma_f32_16x16x32_bf16(a[mf], bb[nf], acc[mf][nf], 0, 0, 0);

    if (MODE == 0 && ks < 11) storeB0(nxt);   // pv dep-wait overlaps MFMA above
    __syncthreads();
    cur = nxt;
  }

  // ---- LN stats combine (MODE 0): block saw all 384 ch of its 256 px
  if (MODE == 0) {
#pragma unroll
    for (int i = 0; i < 4; ++i) {
      sredS[w][4 * l + i] = sum4[i];
      sredQ[w][4 * l + i] = sq4[i];
    }
    __syncthreads();
    if (tid < 256) {
      float s = 0.f, q2 = 0.f;
#pragma unroll
      for (int g = 0; g < 8; ++g) { s += sredS[g][tid]; q2 += sredQ[g][tid]; }
      float mn = s * (1.f / 384.f);
      float var = q2 * (1.f / 384.f) - mn * mn;
      muL[tid] = mn;
      sdL[tid] = rsqrtf(var + 1e-5f);
    }
    __syncthreads();
  }

  // ---- epilogue
#pragma unroll
  for (int nf = 0; nf < 4; ++nf) {
    int row = wn * 64 + nf * 16 + lr;
    int p = pt * 256 + row;
    float m_ = 0.f, s_ = 0.f;
    if (MODE == 0) { m_ = muL[row]; s_ = sdL[row]; }
#pragma unroll
    for (int mf = 0; mf < 4; ++mf) {
#pragma unroll
      for (int r = 0; r < 4; ++r) {
        int o = ot * 128 + wm * 64 + mf * 16 + lg * 4 + r;
        if (MODE == 0) {
          if (o < M) {
            float v = s_ * (acc[mf][nf][r] - m_ * rowsum[o]) + bias[o];
            ((u16*)outv)[((size_t)(b * M + o)) * HW + p] = f2b(v);
          }
        } else {
          ((float*)outv)[((size_t)(b * CDIM + o)) * HW + p] = acc[mf][nf][r];
        }
      }
    }
  }
}

// ---------------------------------------------------------------------------
// k4: depthwise 3x3 (zero pad), LDS-staged plane + fused row l2-norm.
// ---------------------------------------------------------------------------
__global__ __launch_bounds__(256) void k4_dw(const u16* __restrict__ qp, const u16* __restrict__ kvp,
                                             const float* __restrict__ wqdw, const float* __restrict__ wkvdw,
                                             u16* __restrict__ qd, u16* __restrict__ kvd,
                                             float* __restrict__ rnq, float* __restrict__ rnk) {
  __shared__ u16 plane[16384];     // 32 KB
  __shared__ float red[256];

  int c = blockIdx.x, b = blockIdx.y;
  int tid = threadIdx.x;
  const u16* in; u16* outb; const float* wp; int C;
  int isQ = (c < 384), cc = isQ ? c : c - 384;
  if (isQ) { in = qp; outb = qd; wp = wqdw + cc * 9; C = CDIM; }
  else     { in = kvp; outb = kvd; wp = wkvdw + cc * 9; C = KVC; }
  size_t base = ((size_t)(b * C + cc)) * HW;

  float w[9];
#pragma unroll
  for (int j = 0; j < 9; ++j) w[j] = wp[j];

  const uint4* gsrc = (const uint4*)(in + base);
  uint4* lplane = (uint4*)plane;
#pragma unroll
  for (int i = 0; i < 8; ++i) lplane[tid + i * 256] = gsrc[tid + i * 256];
  __syncthreads();

  uint4* gdst = (uint4*)(outb + base);
  float ns = 0.f;
#pragma unroll
  for (int it = 0; it < 8; ++it) {
    int idx = tid + it * 256;
    int y = idx >> 4, ox = idx & 15;
    int x0 = ox * 8;

    float r[3][10];
#pragma unroll
    for (int rr = 0; rr < 3; ++rr) {
      int yy = y + rr - 1;
      if ((unsigned)yy < 128u) {
        int rbase = yy * 128 + x0;
        r[rr][0] = (x0 > 0) ? b2f(plane[rbase - 1]) : 0.f;
        uint4 v = *(const uint4*)&plane[rbase];
        u32 ws[4] = {v.x, v.y, v.z, v.w};
#pragma unroll
        for (int j = 0; j < 4; ++j) {
          r[rr][1 + 2 * j] = b2f((u16)(ws[j] & 0xffff));
          r[rr][2 + 2 * j] = b2f((u16)(ws[j] >> 16));
        }
        r[rr][9] = (x0 < 120) ? b2f(plane[rbase + 8]) : 0.f;
      } else {
#pragma unroll
        for (int j = 0; j < 10; ++j) r[rr][j] = 0.f;
      }
    }

    u32 packed[4];
#pragma unroll
    for (int j = 0; j < 8; ++j) {
      float a = 0.f;
#pragma unroll
      for (int rr = 0; rr < 3; ++rr)
#pragma unroll
        for (int dx = 0; dx < 3; ++dx)
          a += w[rr * 3 + dx] * r[rr][j + dx];
      u16 h = f2b(a);
      float hv = b2f(h);
      ns += hv * hv;
      if (j & 1) packed[j >> 1] |= ((u32)h) << 16; else packed[j >> 1] = (u32)h;
    }
    gdst[idx] = make_uint4(packed[0], packed[1], packed[2], packed[3]);
  }

  red[tid] = ns;
  __syncthreads();
  for (int st = 128; st > 0; st >>= 1) {
    if (tid < st) red[tid] += red[tid + st];
    __syncthreads();
  }
  if (tid == 0) {
    float n = sqrtf(red[0]);
    float inv = 1.f / fmaxf(n, 1e-12f);
    if (isQ) rnq[b * 384 + cc] = inv;
    else if (cc < 96) rnk[b * 96 + cc] = inv;
  }
}

// ---------------------------------------------------------------------------
// k5b: transpose v (kvd rows 96..191) -> vt [b][p][96] bf16. grid (64, 8).
// ---------------------------------------------------------------------------
__global__ void k5b_vt(const u16* __restrict__ kvd, u16* __restrict__ vt) {
  int p = blockIdx.x * 256 + threadIdx.x;
  int b = blockIdx.y;
  size_t sb = ((size_t)(b * KVC + 96)) * HW + p;
  uint4* dv = (uint4*)vt + ((size_t)(b * HW + p)) * 12;
  for (int j8 = 0; j8 < 12; ++j8) {
    u32 w[4];
#pragma unroll
    for (int j = 0; j < 8; ++j) {
      u16 h = kvd[sb + (size_t)(j8 * 8 + j) * HW];
      if (j & 1) w[j >> 1] |= ((u32)h) << 16; else w[j >> 1] = (u32)h;
    }
    dv[j8] = make_uint4(w[0], w[1], w[2], w[3]);
  }
}

// ---------------------------------------------------------------------------
// k6: split-K QK^T partials. grid (16, 8, 8).
// ---------------------------------------------------------------------------
__global__ __launch_bounds__(256) void k6_qk(const u16* __restrict__ qd,
                                             const u16* __restrict__ kvd,
                                             float* __restrict__ spart) {
  int kc = blockIdx.x, h = blockIdx.y, b = blockIdx.z;
  int tid = threadIdx.x;
  int w = tid >> 6, l = tid & 63, lr = l & 15, lg = l >> 4;
  int g = h >> 2;
  int p0 = kc * 1024 + w * 256;

  f32x4 acc[3][3] = {};
  size_t qbase = ((size_t)(b * CDIM + h * 48 + lr)) * HW;
  size_t kbase = ((size_t)(b * KVC + g * 48 + lr)) * HW;

  for (int ks = 0; ks < 8; ++ks) {
    int pp = p0 + ks * 32 + lg * 8;
    s16x8 a[3], bb[3];
#pragma unroll
    for (int mi = 0; mi < 3; ++mi) a[mi] = *(const s16x8*)(qd + qbase + (size_t)mi * 16 * HW + pp);
#pragma unroll
    for (int ni = 0; ni < 3; ++ni) bb[ni] = *(const s16x8*)(kvd + kbase + (size_t)ni * 16 * HW + pp);
#pragma unroll
    for (int mi = 0; mi < 3; ++mi)
#pragma unroll
      for (int ni = 0; ni < 3; ++ni)
        acc[mi][ni] = __builtin_amdgcn_mfma_f32_16x16x32_bf16(a[mi], bb[ni], acc[mi][ni], 0, 0, 0);
  }

  size_t sb = ((size_t)((((b * 8 + h) * 16) + kc) * 4 + w)) * 2304;
#pragma unroll
  for (int mi = 0; mi < 3; ++mi)
#pragma unroll
    for (int ni = 0; ni < 3; ++ni)
#pragma unroll
      for (int r = 0; r < 4; ++r) {
        int c = mi * 16 + lg * 4 + r, d = ni * 16 + lr;
        spart[sb + c * 48 + d] = acc[mi][ni][r];
      }
}

// ---------------------------------------------------------------------------
// k7: reduce partials + scale + softmax -> P~ [b][384][96] bf16.
// ---------------------------------------------------------------------------
__global__ void k7_sm(const float* __restrict__ spart, const float* __restrict__ temp,
                      const float* __restrict__ rnq, const float* __restrict__ rnk,
                      u16* __restrict__ ptil) {
  int h = blockIdx.x, b = blockIdx.y, tid = threadIdx.x;
  int g = h >> 2;
  __shared__ float S[2304];
  size_t base = ((size_t)((b * 8 + h) * 64)) * 2304;
  for (int e = tid; e < 2304; e += 64) {
    float s = 0.f;
    for (int j = 0; j < 64; ++j) s += spart[base + (size_t)j * 2304 + e];
    S[e] = s;
  }
  __syncthreads();
  if (tid < 48) {
    int c = tid;
    float sq = temp[h] * rnq[b * 384 + h * 48 + c];
    float mx = -1e30f;
    for (int d = 0; d < 48; ++d) {
      float v = S[c * 48 + d] * sq * rnk[b * 96 + g * 48 + d];
      mx = fmaxf(mx, v);
    }
    float sum = 0.f;
    for (int d = 0; d < 48; ++d) {
      float v = S[c * 48 + d] * sq * rnk[b * 96 + g * 48 + d];
      sum += __expf(v - mx);
    }
    float inv = 1.f / sum;
    u16* row = ptil + ((size_t)(b * 384 + h * 48 + c)) * 96;
    for (int dk = 0; dk < 96; ++dk) {
      int d = dk - g * 48;
      float pv = 0.f;
      if (d >= 0 && d < 48) {
        float v = S[c * 48 + d] * sq * rnk[b * 96 + g * 48 + d];
        pv = __expf(v - mx) * inv;
      }
      row[dk] = f2b(pv);
    }
  }
}

// ---------------------------------------------------------------------------
// k8: Yt[p][c] = sum_dk vt[p][dk] * P~[c][dk].  grid (128, 8), 512 thr.
// ---------------------------------------------------------------------------
__global__ __launch_bounds__(512) void k8_pv(const u16* __restrict__ vt,
                                             const u16* __restrict__ ptil,
                                             u16* __restrict__ yt) {
  int ptb = blockIdx.x, b = blockIdx.y;
  int tid = threadIdx.x;
  int w = tid >> 6, l = tid & 63, lr = l & 15, lg = l >> 4;
  int wm = w >> 2, wn = w & 3;

  f32x4 acc[4][6] = {};
  size_t arow0 = ((size_t)(b * HW + ptb * 128 + wm * 64 + lr)) * 96;
  size_t brow0 = ((size_t)(b * CDIM + wn * 96 + lr)) * 96;

  for (int ks = 0; ks < 3; ++ks) {
    int ko = ks * 32 + lg * 8;
    s16x8 a[4], bb[6];
#pragma unroll
    for (int mf = 0; mf < 4; ++mf) a[mf] = *(const s16x8*)(vt + arow0 + (size_t)mf * 16 * 96 + ko);
#pragma unroll
    for (int nf = 0; nf < 6; ++nf) bb[nf] = *(const s16x8*)(ptil + brow0 + (size_t)nf * 16 * 96 + ko);
#pragma unroll
    for (int mf = 0; mf < 4; ++mf)
#pragma unroll
      for (int nf = 0; nf < 6; ++nf)
        acc[mf][nf] = __builtin_amdgcn_mfma_f32_16x16x32_bf16(a[mf], bb[nf], acc[mf][nf], 0, 0, 0);
  }

#pragma unroll
  for (int mf = 0; mf < 4; ++mf)
#pragma unroll
    for (int nf = 0; nf < 6; ++nf)
#pragma unroll
      for (int r = 0; r < 4; ++r) {
        int p = ptb * 128 + wm * 64 + mf * 16 + lg * 4 + r;
        int c = wn * 96 + nf * 16 + lr;
        yt[((size_t)(b * HW + p)) * 384 + c] = f2b(acc[mf][nf][r]);
      }
}

// ---------------------------------------------------------------------------
extern "C" void kernel_launch(void* const* d_in, const int* in_sizes, int n_in,
                              void* d_out, int out_size, void* d_ws, size_t ws_size,
                              hipStream_t stream) {
  const float* q    = (const float*)d_in[0];
  const float* k    = (const float*)d_in[1];
  const float* w_q  = (const float*)d_in[2];
  const float* w_kv = (const float*)d_in[3];
  const float* w_qd = (const float*)d_in[4];
  const float* w_kd = (const float*)d_in[5];
  const float* w_o  = (const float*)d_in[6];
  const float* temp = (const float*)d_in[7];
  const float* lnqw = (const float*)d_in[8];
  const float* lnqb = (const float*)d_in[9];
  const float* lnkw = (const float*)d_in[10];
  const float* lnkb = (const float*)d_in[11];
  float* out = (float*)d_out;

  char* ws = (char*)d_ws;
  size_t off = 0;
  auto alloc = [&](size_t bytes) -> void* {
    void* p = ws + off;
    off += (bytes + 255) & ~(size_t)255;
    return p;
  };

  u16*   wqp   = (u16*)alloc(384 * 384 * 2);
  float* rwsQ  = (float*)alloc(384 * 4);
  float* biasQ = (float*)alloc(384 * 4);
  u16*   wkvp  = (u16*)alloc(256 * 384 * 2);   // padded to 256 rows
  float* rwsKV = (float*)alloc(256 * 4);
  float* biasKV= (float*)alloc(256 * 4);
  u16*   wop   = (u16*)alloc(384 * 384 * 2);
  u16*   qp    = (u16*)alloc((size_t)NB * CDIM * HW * 2);  // aliased as yt later
  u16*   kvp   = (u16*)alloc((size_t)NB * KVC * HW * 2);
  u16*   qd    = (u16*)alloc((size_t)NB * CDIM * HW * 2);
  u16*   kvd   = (u16*)alloc((size_t)NB * KVC * HW * 2);
  u16*   vt    = (u16*)alloc((size_t)NB * HW * 96 * 2);
  float* spart = (float*)alloc((size_t)4096 * 2304 * 4);
  u16*   ptil  = (u16*)alloc((size_t)NB * CDIM * 96 * 2);
  float* rnq   = (float*)alloc((size_t)NB * 384 * 4);
  float* rnk   = (float*)alloc((size_t)NB * 96 * 4);

  // lifetime alias (sequential stream => safe): qp dead after k4
  u16* yt = qp;

  k0_prep<<<4, 256, 0, stream>>>(w_q, w_kv, w_o, lnqw, lnqb, lnkw, lnkb,
                                 wqp, rwsQ, biasQ, wkvp, rwsKV, biasKV, wop);

  gemm_fused<0><<<dim3(64, 3, NB), 512, 0, stream>>>(wqp, q, rwsQ, biasQ, qp, 384);
  gemm_fused<0><<<dim3(64, 2, NB), 512, 0, stream>>>(wkvp, k, rwsKV, biasKV, kvp, 192);

  k4_dw<<<dim3(576, NB), 256, 0, stream>>>(qp, kvp, w_qd, w_kd, qd, kvd, rnq, rnk);

  k5b_vt<<<dim3(64, NB), 256, 0, stream>>>(kvd, vt);

  k6_qk<<<dim3(16, 8, NB), 256, 0, stream>>>(qd, kvd, spart);
  k7_sm<<<dim3(8, NB), 64, 0, stream>>>(spart, temp, rnq, rnk, ptil);

  k8_pv<<<dim3(128, NB), 512, 0, stream>>>(vt, ptil, yt);

  gemm_fused<1><<<dim3(64, 3, NB), 512, 0, stream>>>(wop, yt, nullptr, nullptr, out, 384);
}

// Round 9
// 712.672 us; speedup vs baseline: 1.9255x; 1.9255x over previous
//
#include <hip/hip_runtime.h>
#include <math.h>

// ---------------------------------------------------------------------------
// CrossGroupedQueryAttention on MI355X — round 9
//
// R8 post-mortem: REGRESSION (1372us). acc[4][4]=64 VGPR + pv + frags blew the
// 128-reg cap -> scratch spills (WRITE 1.35GB vs 100MB real output, MfmaUtil
// 2.4%). Lesson: accumulator budget <=32 regs. Salvage: chip sustained 3.5TB/s
// -> DRAM geometry was never the wall.
// R9: producer/consumer wave specialization (the guide's named path past the
// barrier-drain). 512 thr: waves 0-3 consume (LDS->MFMA only, acc[2][4]=32),
// waves 4-7 produce (all global traffic). B f32 HBM loads live ONLY on
// producer waves and are NEVER drained at barriers (producers end steps with
// lgkmcnt(0) only; pv reg deps auto-waited one step later). MODE1: 3-buf gll
// pipeline with counted vmcnt(2) (gll is producer's only vmem -> count robust).
// Consumers' only vmem = L2-hot A-gll, vmcnt(0) hidden under MFMA.
// Grid: ot innermost so ot-blocks sharing a B-tile run concurrently (L2 reuse).
// ---------------------------------------------------------------------------

typedef unsigned short u16;
typedef unsigned int u32;
typedef short s16x8 __attribute__((ext_vector_type(8)));
typedef float f32x4 __attribute__((ext_vector_type(4)));

#define HW 16384
#define NB 8
#define CDIM 384
#define KVC 192

__device__ __forceinline__ float b2f(u16 u) {
  return __uint_as_float(((u32)u) << 16);
}
__device__ __forceinline__ u16 f2b(float f) {
  u32 u = __float_as_uint(f);
  u += 0x7fffu + ((u >> 16) & 1u);   // RNE
  return (u16)(u >> 16);
}
__device__ __forceinline__ u32 pack2(float a, float c) {
  return (u32)f2b(a) | ((u32)f2b(c) << 16);
}
__device__ __forceinline__ int swz(int r) {          // LDS chunk swizzle
  return (r & 3) ^ ((r >> 2) & 3) ^ ((r >> 4) & 3);
}
__device__ __forceinline__ void gll16(const void* g, void* l) {
  __builtin_amdgcn_global_load_lds(
      (const __attribute__((address_space(1))) u32*)g,
      (__attribute__((address_space(3))) u32*)l, 16, 0, 0);
}

// ---------------------------------------------------------------------------
// k0: fold LN weights into conv weights.  1024 threads.
// ---------------------------------------------------------------------------
__global__ void k0_prep(const float* __restrict__ wq, const float* __restrict__ wkv,
                        const float* __restrict__ wo,
                        const float* __restrict__ lnqw, const float* __restrict__ lnqb,
                        const float* __restrict__ lnkw, const float* __restrict__ lnkb,
                        u16* __restrict__ wqp, float* __restrict__ rwsQ, float* __restrict__ biasQ,
                        u16* __restrict__ wkvp, float* __restrict__ rwsKV, float* __restrict__ biasKV,
                        u16* __restrict__ wop) {
  int r = blockIdx.x * 256 + threadIdx.x;
  if (r < 384) {
    float rs = 0.f, bs = 0.f;
    for (int i = 0; i < 384; ++i) {
      float wp = wq[r * 384 + i] * lnqw[i];
      u16 h = f2b(wp);
      rs += b2f(h);
      bs += wq[r * 384 + i] * lnqb[i];
      wqp[r * 384 + i] = h;
    }
    rwsQ[r] = rs; biasQ[r] = bs;
  } else if (r < 640) {
    int o = r - 384;
    if (o < 192) {
      float rs = 0.f, bs = 0.f;
      for (int i = 0; i < 384; ++i) {
        float wp = wkv[o * 384 + i] * lnkw[i];
        u16 h = f2b(wp);
        rs += b2f(h);
        bs += wkv[o * 384 + i] * lnkb[i];
        wkvp[o * 384 + i] = h;
      }
      rwsKV[o] = rs; biasKV[o] = bs;
    } else {
      for (int i = 0; i < 384; ++i) wkvp[o * 384 + i] = 0;
      rwsKV[o] = 0.f; biasKV[o] = 0.f;
    }
  } else {
    int o = r - 640;
    for (int i = 0; i < 384; ++i) wop[o * 384 + i] = f2b(wo[o * 384 + i]);
  }
}

// ---------------------------------------------------------------------------
// gemm_fused: D[o][p] = sum_k A[o][k]*B[p][k], K=384, tile 64o x 128p,
// 512 thr: waves 0-3 consumers (2m x 2n, wave-tile 32x64, acc[2][4]=32 regs),
// waves 4-7 producers (all B traffic).
// A: 4KB/step via gll16 by consumers (1-ahead, 2-buf, pre-swizzled src).
// MODE 0: producers read B f32 NCHW as float2 (512B/instr), 2-step-deep reg
//   pipeline (pv0/pv1), cvt+LN-stats, ds_write_b128 into stride-34 tB (2-buf);
//   producer barrier-wait = lgkmcnt(0) ONLY -> HBM loads never drained.
// MODE 1: producers gll B (yt bf16) 2-ahead into 3-buf tB, wait vmcnt(2).
// Epilogue by consumers; LN stats combined from producer partials.
// ---------------------------------------------------------------------------
template <int MODE>
__global__ __launch_bounds__(512, 4) void gemm_fused(const u16* __restrict__ A,
                                                     const void* __restrict__ Bsrc,
                                                     const float* __restrict__ rowsum,
                                                     const float* __restrict__ bias,
                                                     void* __restrict__ outv, int M, int nOt) {
  __shared__ u16 tA[2][64 * 32];
  __shared__ u16 tB[MODE == 0 ? 2 : 3][MODE == 0 ? 128 * 34 : 128 * 32];
  __shared__ float sredS[MODE == 0 ? 4 : 1][MODE == 0 ? 128 : 1];
  __shared__ float sredQ[MODE == 0 ? 4 : 1][MODE == 0 ? 128 : 1];
  __shared__ float muL[MODE == 0 ? 128 : 1], sdL[MODE == 0 ? 128 : 1];

  const int b = blockIdx.z;
  const int ot = (int)(blockIdx.x % (unsigned)nOt);
  const int pt = (int)(blockIdx.x / (unsigned)nOt);
  const int tid = threadIdx.x;
  const int w = tid >> 6, l = tid & 63;
  const bool consumer = (w < 4);
  const int lr = l & 15, lg = l >> 4;
  const int wm = w >> 1, wn = w & 1;          // consumer 2x2

  f32x4 acc[2][4] = {};

  // ---- consumer A-gll mapping (256 lanes): row tid>>2, chunk tid&3
  const int rA = tid >> 2, cA = tid & 3;
  const u16* aS = A + (size_t)(ot * 64 + rA) * 384 + (cA ^ swz(rA)) * 8;

  // ---- producer mappings
  const int tid2 = tid - 256;                  // 0..255 on producers
  const int pl = tid2 & 63, pw = (tid2 >> 6) & 3;
  const float* Bf = (const float*)Bsrc;
  const u16* Bh = (const u16*)Bsrc;
  // MODE 0: lane pl -> px pair {2pl, 2pl+1}; wave pw -> 8 channels pw*8+e
  const float* fbase = Bf + (size_t)b * CDIM * HW + (size_t)pt * 128 + 2 * pl;
  // MODE 1: 2 glls: rows tid2>>2 and 64+(tid2>>2)
  const int rB = tid2 >> 2, cB = tid2 & 3;
  const u16* bS0 = Bh + ((size_t)(b * HW + pt * 128 + rB)) * 384 + (cB ^ swz(rB)) * 8;
  const u16* bS1 = Bh + ((size_t)(b * HW + pt * 128 + 64 + rB)) * 384 + (cB ^ swz(64 + rB)) * 8;

  float2 pv0[8], pv1[8];
  float s0 = 0.f, s1 = 0.f, q0 = 0.f, q1 = 0.f;

  auto stageA = [&](int ks, int buf) {         // consumers, waves 0..3
    gll16(aS + ks * 32, &tA[buf][w * 512]);
  };
  auto stageB1 = [&](int ks, int buf) {        // producers (MODE 1)
    gll16(bS0 + ks * 32, &tB[buf][pw * 512]);
    gll16(bS1 + ks * 32, &tB[buf][2048 + pw * 512]);
  };
  auto loadB = [&](int ks, float2* pv) {       // producers (MODE 0): 8 x 512B
#pragma unroll
    for (int e = 0; e < 8; ++e)
      pv[e] = *(const float2*)(fbase + (size_t)(ks * 32 + pw * 8 + e) * HW);
  };
  auto packB = [&](const float2* pv, int buf) { // cvt + stats + b128 writes
    u32 pkA[4], pkB[4];
#pragma unroll
    for (int j = 0; j < 4; ++j) {
      float a0 = pv[2 * j].x, b0 = pv[2 * j + 1].x;
      float a1 = pv[2 * j].y, b1 = pv[2 * j + 1].y;
      s0 += a0 + b0; q0 += a0 * a0 + b0 * b0;
      s1 += a1 + b1; q1 += a1 * a1 + b1 * b1;
      pkA[j] = pack2(a0, b0);
      pkB[j] = pack2(a1, b1);
    }
    *(uint4*)&tB[buf][(2 * pl) * 34 + pw * 8]     = make_uint4(pkA[0], pkA[1], pkA[2], pkA[3]);
    *(uint4*)&tB[buf][(2 * pl + 1) * 34 + pw * 8] = make_uint4(pkB[0], pkB[1], pkB[2], pkB[3]);
  };

  // ---- prologue
  if (consumer) {
    stageA(0, 0);
    asm volatile("s_waitcnt vmcnt(0)" ::: "memory");
  } else {
    if (MODE == 0) {
      loadB(0, pv0);
      loadB(1, pv1);
      packB(pv0, 0);                            // compiler waits pv0's loads
      asm volatile("s_waitcnt lgkmcnt(0)" ::: "memory");
    } else {
      stageB1(0, 0);
      stageB1(1, 1);
      asm volatile("s_waitcnt vmcnt(2)" ::: "memory");  // step-0 glls done
    }
  }
  __builtin_amdgcn_s_barrier();

#pragma unroll
  for (int ks = 0; ks < 12; ++ks) {
    if (consumer) {
      if (ks < 11) stageA(ks + 1, (ks + 1) & 1);
      const int cbA = ks & 1;
      const int cbB = (MODE == 0) ? (ks & 1) : (ks % 3);
      s16x8 a[2], bb[4];
#pragma unroll
      for (int mf = 0; mf < 2; ++mf) {
        int row = wm * 32 + mf * 16 + lr;
        a[mf] = *(const s16x8*)&tA[cbA][row * 32 + (lg ^ swz(row)) * 8];
      }
#pragma unroll
      for (int nf = 0; nf < 4; ++nf) {
        int row = wn * 64 + nf * 16 + lr;
        if (MODE == 0) bb[nf] = *(const s16x8*)&tB[cbB][row * 34 + lg * 8];
        else           bb[nf] = *(const s16x8*)&tB[cbB][row * 32 + (lg ^ swz(row)) * 8];
      }
#pragma unroll
      for (int mf = 0; mf < 2; ++mf)
#pragma unroll
        for (int nf = 0; nf < 4; ++nf)
          acc[mf][nf] = __builtin_amdgcn_mfma_f32_16x16x32_bf16(a[mf], bb[nf], acc[mf][nf], 0, 0, 0);
      asm volatile("s_waitcnt vmcnt(0)" ::: "memory");   // A-gll retired (L2-hot)
    } else {
      if (MODE == 0) {
        if (ks < 10) loadB(ks + 2, (ks & 1) ? pv1 : pv0);
        if (ks < 11) packB((ks & 1) ? pv0 : pv1, (ks + 1) & 1);
        asm volatile("s_waitcnt lgkmcnt(0)" ::: "memory"); // ds_writes visible; HBM loads stay in flight
      } else {
        if (ks < 10) {
          stageB1(ks + 2, (ks + 2) % 3);
          asm volatile("s_waitcnt vmcnt(2)" ::: "memory"); // (ks+1)'s glls done, (ks+2)'s fly
        } else {
          asm volatile("s_waitcnt vmcnt(0)" ::: "memory"); // tail drain
        }
      }
    }
    __builtin_amdgcn_s_barrier();
  }

  // ---- LN stats combine (MODE 0): producers hold 96-ch partials per px
  if (MODE == 0) {
    if (!consumer) {
      sredS[pw][2 * pl] = s0;     sredQ[pw][2 * pl] = q0;
      sredS[pw][2 * pl + 1] = s1; sredQ[pw][2 * pl + 1] = q1;
    }
    __syncthreads();
    if (tid < 128) {
      float s = 0.f, q2 = 0.f;
#pragma unroll
      for (int g = 0; g < 4; ++g) { s += sredS[g][tid]; q2 += sredQ[g][tid]; }
      float mn = s * (1.f / 384.f);
      float var = q2 * (1.f / 384.f) - mn * mn;
      muL[tid] = mn;
      sdL[tid] = rsqrtf(var + 1e-5f);
    }
    __syncthreads();
  }

  // ---- epilogue (consumers only)
  if (consumer) {
#pragma unroll
    for (int nf = 0; nf < 4; ++nf) {
      int row = wn * 64 + nf * 16 + lr;
      int p = pt * 128 + row;
      float m_ = 0.f, s_ = 0.f;
      if (MODE == 0) { m_ = muL[row]; s_ = sdL[row]; }
#pragma unroll
      for (int mf = 0; mf < 2; ++mf) {
#pragma unroll
        for (int r = 0; r < 4; ++r) {
          int o = ot * 64 + wm * 32 + mf * 16 + lg * 4 + r;
          if (MODE == 0) {
            float v = s_ * (acc[mf][nf][r] - m_ * rowsum[o]) + bias[o];
            ((u16*)outv)[((size_t)(b * M + o)) * HW + p] = f2b(v);
          } else {
            ((float*)outv)[((size_t)(b * CDIM + o)) * HW + p] = acc[mf][nf][r];
          }
        }
      }
    }
  }
}

// ---------------------------------------------------------------------------
// k4: depthwise 3x3 (zero pad), LDS-staged plane + fused row l2-norm.
// ---------------------------------------------------------------------------
__global__ __launch_bounds__(256) void k4_dw(const u16* __restrict__ qp, const u16* __restrict__ kvp,
                                             const float* __restrict__ wqdw, const float* __restrict__ wkvdw,
                                             u16* __restrict__ qd, u16* __restrict__ kvd,
                                             float* __restrict__ rnq, float* __restrict__ rnk) {
  __shared__ u16 plane[16384];     // 32 KB
  __shared__ float red[256];

  int c = blockIdx.x, b = blockIdx.y;
  int tid = threadIdx.x;
  const u16* in; u16* outb; const float* wp; int C;
  int isQ = (c < 384), cc = isQ ? c : c - 384;
  if (isQ) { in = qp; outb = qd; wp = wqdw + cc * 9; C = CDIM; }
  else     { in = kvp; outb = kvd; wp = wkvdw + cc * 9; C = KVC; }
  size_t base = ((size_t)(b * C + cc)) * HW;

  float w[9];
#pragma unroll
  for (int j = 0; j < 9; ++j) w[j] = wp[j];

  const uint4* gsrc = (const uint4*)(in + base);
  uint4* lplane = (uint4*)plane;
#pragma unroll
  for (int i = 0; i < 8; ++i) lplane[tid + i * 256] = gsrc[tid + i * 256];
  __syncthreads();

  uint4* gdst = (uint4*)(outb + base);
  float ns = 0.f;
#pragma unroll
  for (int it = 0; it < 8; ++it) {
    int idx = tid + it * 256;
    int y = idx >> 4, ox = idx & 15;
    int x0 = ox * 8;

    float r[3][10];
#pragma unroll
    for (int rr = 0; rr < 3; ++rr) {
      int yy = y + rr - 1;
      if ((unsigned)yy < 128u) {
        int rbase = yy * 128 + x0;
        r[rr][0] = (x0 > 0) ? b2f(plane[rbase - 1]) : 0.f;
        uint4 v = *(const uint4*)&plane[rbase];
        u32 ws[4] = {v.x, v.y, v.z, v.w};
#pragma unroll
        for (int j = 0; j < 4; ++j) {
          r[rr][1 + 2 * j] = b2f((u16)(ws[j] & 0xffff));
          r[rr][2 + 2 * j] = b2f((u16)(ws[j] >> 16));
        }
        r[rr][9] = (x0 < 120) ? b2f(plane[rbase + 8]) : 0.f;
      } else {
#pragma unroll
        for (int j = 0; j < 10; ++j) r[rr][j] = 0.f;
      }
    }

    u32 packed[4];
#pragma unroll
    for (int j = 0; j < 8; ++j) {
      float a = 0.f;
#pragma unroll
      for (int rr = 0; rr < 3; ++rr)
#pragma unroll
        for (int dx = 0; dx < 3; ++dx)
          a += w[rr * 3 + dx] * r[rr][j + dx];
      u16 h = f2b(a);
      float hv = b2f(h);
      ns += hv * hv;
      if (j & 1) packed[j >> 1] |= ((u32)h) << 16; else packed[j >> 1] = (u32)h;
    }
    gdst[idx] = make_uint4(packed[0], packed[1], packed[2], packed[3]);
  }

  red[tid] = ns;
  __syncthreads();
  for (int st = 128; st > 0; st >>= 1) {
    if (tid < st) red[tid] += red[tid + st];
    __syncthreads();
  }
  if (tid == 0) {
    float n = sqrtf(red[0]);
    float inv = 1.f / fmaxf(n, 1e-12f);
    if (isQ) rnq[b * 384 + cc] = inv;
    else if (cc < 96) rnk[b * 96 + cc] = inv;
  }
}

// ---------------------------------------------------------------------------
// k5b: transpose v (kvd rows 96..191) -> vt [b][p][96] bf16. grid (64, 8).
// ---------------------------------------------------------------------------
__global__ void k5b_vt(const u16* __restrict__ kvd, u16* __restrict__ vt) {
  int p = blockIdx.x * 256 + threadIdx.x;
  int b = blockIdx.y;
  size_t sb = ((size_t)(b * KVC + 96)) * HW + p;
  uint4* dv = (uint4*)vt + ((size_t)(b * HW + p)) * 12;
  for (int j8 = 0; j8 < 12; ++j8) {
    u32 w[4];
#pragma unroll
    for (int j = 0; j < 8; ++j) {
      u16 h = kvd[sb + (size_t)(j8 * 8 + j) * HW];
      if (j & 1) w[j >> 1] |= ((u32)h) << 16; else w[j >> 1] = (u32)h;
    }
    dv[j8] = make_uint4(w[0], w[1], w[2], w[3]);
  }
}

// ---------------------------------------------------------------------------
// k6: split-K QK^T partials. grid (16, 8, 8).
// ---------------------------------------------------------------------------
__global__ __launch_bounds__(256) void k6_qk(const u16* __restrict__ qd,
                                             const u16* __restrict__ kvd,
                                             float* __restrict__ spart) {
  int kc = blockIdx.x, h = blockIdx.y, b = blockIdx.z;
  int tid = threadIdx.x;
  int w = tid >> 6, l = tid & 63, lr = l & 15, lg = l >> 4;
  int g = h >> 2;
  int p0 = kc * 1024 + w * 256;

  f32x4 acc[3][3] = {};
  size_t qbase = ((size_t)(b * CDIM + h * 48 + lr)) * HW;
  size_t kbase = ((size_t)(b * KVC + g * 48 + lr)) * HW;

  for (int ks = 0; ks < 8; ++ks) {
    int pp = p0 + ks * 32 + lg * 8;
    s16x8 a[3], bb[3];
#pragma unroll
    for (int mi = 0; mi < 3; ++mi) a[mi] = *(const s16x8*)(qd + qbase + (size_t)mi * 16 * HW + pp);
#pragma unroll
    for (int ni = 0; ni < 3; ++ni) bb[ni] = *(const s16x8*)(kvd + kbase + (size_t)ni * 16 * HW + pp);
#pragma unroll
    for (int mi = 0; mi < 3; ++mi)
#pragma unroll
      for (int ni = 0; ni < 3; ++ni)
        acc[mi][ni] = __builtin_amdgcn_mfma_f32_16x16x32_bf16(a[mi], bb[ni], acc[mi][ni], 0, 0, 0);
  }

  size_t sb = ((size_t)((((b * 8 + h) * 16) + kc) * 4 + w)) * 2304;
#pragma unroll
  for (int mi = 0; mi < 3; ++mi)
#pragma unroll
    for (int ni = 0; ni < 3; ++ni)
#pragma unroll
      for (int r = 0; r < 4; ++r) {
        int c = mi * 16 + lg * 4 + r, d = ni * 16 + lr;
        spart[sb + c * 48 + d] = acc[mi][ni][r];
      }
}

// ---------------------------------------------------------------------------
// k7: reduce partials + scale + softmax -> P~ [b][384][96] bf16.
// ---------------------------------------------------------------------------
__global__ void k7_sm(const float* __restrict__ spart, const float* __restrict__ temp,
                      const float* __restrict__ rnq, const float* __restrict__ rnk,
                      u16* __restrict__ ptil) {
  int h = blockIdx.x, b = blockIdx.y, tid = threadIdx.x;
  int g = h >> 2;
  __shared__ float S[2304];
  size_t base = ((size_t)((b * 8 + h) * 64)) * 2304;
  for (int e = tid; e < 2304; e += 64) {
    float s = 0.f;
    for (int j = 0; j < 64; ++j) s += spart[base + (size_t)j * 2304 + e];
    S[e] = s;
  }
  __syncthreads();
  if (tid < 48) {
    int c = tid;
    float sq = temp[h] * rnq[b * 384 + h * 48 + c];
    float mx = -1e30f;
    for (int d = 0; d < 48; ++d) {
      float v = S[c * 48 + d] * sq * rnk[b * 96 + g * 48 + d];
      mx = fmaxf(mx, v);
    }
    float sum = 0.f;
    for (int d = 0; d < 48; ++d) {
      float v = S[c * 48 + d] * sq * rnk[b * 96 + g * 48 + d];
      sum += __expf(v - mx);
    }
    float inv = 1.f / sum;
    u16* row = ptil + ((size_t)(b * 384 + h * 48 + c)) * 96;
    for (int dk = 0; dk < 96; ++dk) {
      int d = dk - g * 48;
      float pv = 0.f;
      if (d >= 0 && d < 48) {
        float v = S[c * 48 + d] * sq * rnk[b * 96 + g * 48 + d];
        pv = __expf(v - mx) * inv;
      }
      row[dk] = f2b(pv);
    }
  }
}

// ---------------------------------------------------------------------------
// k8: Yt[p][c] = sum_dk vt[p][dk] * P~[c][dk].  grid (128, 8), 512 thr.
// ---------------------------------------------------------------------------
__global__ __launch_bounds__(512) void k8_pv(const u16* __restrict__ vt,
                                             const u16* __restrict__ ptil,
                                             u16* __restrict__ yt) {
  int ptb = blockIdx.x, b = blockIdx.y;
  int tid = threadIdx.x;
  int w = tid >> 6, l = tid & 63, lr = l & 15, lg = l >> 4;
  int wm = w >> 2, wn = w & 3;

  f32x4 acc[4][6] = {};
  size_t arow0 = ((size_t)(b * HW + ptb * 128 + wm * 64 + lr)) * 96;
  size_t brow0 = ((size_t)(b * CDIM + wn * 96 + lr)) * 96;

  for (int ks = 0; ks < 3; ++ks) {
    int ko = ks * 32 + lg * 8;
    s16x8 a[4], bb[6];
#pragma unroll
    for (int mf = 0; mf < 4; ++mf) a[mf] = *(const s16x8*)(vt + arow0 + (size_t)mf * 16 * 96 + ko);
#pragma unroll
    for (int nf = 0; nf < 6; ++nf) bb[nf] = *(const s16x8*)(ptil + brow0 + (size_t)nf * 16 * 96 + ko);
#pragma unroll
    for (int mf = 0; mf < 4; ++mf)
#pragma unroll
      for (int nf = 0; nf < 6; ++nf)
        acc[mf][nf] = __builtin_amdgcn_mfma_f32_16x16x32_bf16(a[mf], bb[nf], acc[mf][nf], 0, 0, 0);
  }

#pragma unroll
  for (int mf = 0; mf < 4; ++mf)
#pragma unroll
    for (int nf = 0; nf < 6; ++nf)
#pragma unroll
      for (int r = 0; r < 4; ++r) {
        int p = ptb * 128 + wm * 64 + mf * 16 + lg * 4 + r;
        int c = wn * 96 + nf * 16 + lr;
        yt[((size_t)(b * HW + p)) * 384 + c] = f2b(acc[mf][nf][r]);
      }
}

// ---------------------------------------------------------------------------
extern "C" void kernel_launch(void* const* d_in, const int* in_sizes, int n_in,
                              void* d_out, int out_size, void* d_ws, size_t ws_size,
                              hipStream_t stream) {
  const float* q    = (const float*)d_in[0];
  const float* k    = (const float*)d_in[1];
  const float* w_q  = (const float*)d_in[2];
  const float* w_kv = (const float*)d_in[3];
  const float* w_qd = (const float*)d_in[4];
  const float* w_kd = (const float*)d_in[5];
  const float* w_o  = (const float*)d_in[6];
  const float* temp = (const float*)d_in[7];
  const float* lnqw = (const float*)d_in[8];
  const float* lnqb = (const float*)d_in[9];
  const float* lnkw = (const float*)d_in[10];
  const float* lnkb = (const float*)d_in[11];
  float* out = (float*)d_out;

  char* ws = (char*)d_ws;
  size_t off = 0;
  auto alloc = [&](size_t bytes) -> void* {
    void* p = ws + off;
    off += (bytes + 255) & ~(size_t)255;
    return p;
  };

  u16*   wqp   = (u16*)alloc(384 * 384 * 2);
  float* rwsQ  = (float*)alloc(384 * 4);
  float* biasQ = (float*)alloc(384 * 4);
  u16*   wkvp  = (u16*)alloc(256 * 384 * 2);   // padded to 256 rows
  float* rwsKV = (float*)alloc(256 * 4);
  float* biasKV= (float*)alloc(256 * 4);
  u16*   wop   = (u16*)alloc(384 * 384 * 2);
  u16*   qp    = (u16*)alloc((size_t)NB * CDIM * HW * 2);  // aliased as yt later
  u16*   kvp   = (u16*)alloc((size_t)NB * KVC * HW * 2);
  u16*   qd    = (u16*)alloc((size_t)NB * CDIM * HW * 2);
  u16*   kvd   = (u16*)alloc((size_t)NB * KVC * HW * 2);
  u16*   vt    = (u16*)alloc((size_t)NB * HW * 96 * 2);
  float* spart = (float*)alloc((size_t)4096 * 2304 * 4);
  u16*   ptil  = (u16*)alloc((size_t)NB * CDIM * 96 * 2);
  float* rnq   = (float*)alloc((size_t)NB * 384 * 4);
  float* rnk   = (float*)alloc((size_t)NB * 96 * 4);

  // lifetime alias (sequential stream => safe): qp dead after k4
  u16* yt = qp;

  k0_prep<<<4, 256, 0, stream>>>(w_q, w_kv, w_o, lnqw, lnqb, lnkw, lnkb,
                                 wqp, rwsQ, biasQ, wkvp, rwsKV, biasKV, wop);

  // ot innermost: blocks sharing a B-tile run concurrently (L2 reuse)
  gemm_fused<0><<<dim3(6 * 128, 1, NB), 512, 0, stream>>>(wqp, q, rwsQ, biasQ, qp, 384, 6);
  gemm_fused<0><<<dim3(3 * 128, 1, NB), 512, 0, stream>>>(wkvp, k, rwsKV, biasKV, kvp, 192, 3);

  k4_dw<<<dim3(576, NB), 256, 0, stream>>>(qp, kvp, w_qd, w_kd, qd, kvd, rnq, rnk);

  k5b_vt<<<dim3(64, NB), 256, 0, stream>>>(kvd, vt);

  k6_qk<<<dim3(16, 8, NB), 256, 0, stream>>>(qd, kvd, spart);
  k7_sm<<<dim3(8, NB), 64, 0, stream>>>(spart, temp, rnq, rnk, ptil);

  k8_pv<<<dim3(128, NB), 512, 0, stream>>>(vt, ptil, yt);

  gemm_fused<1><<<dim3(6 * 128, 1, NB), 512, 0, stream>>>(wop, yt, nullptr, nullptr, out, 384, 6);
}

// Round 10
// 630.066 us; speedup vs baseline: 2.1779x; 1.1311x over previous
//
#include <hip/hip_runtime.h>
#include <math.h>

// ---------------------------------------------------------------------------
// CrossGroupedQueryAttention on MI355X — round 10
//
// R9 post-mortem: producer/consumer REGRESSED (230us/GEMM): ot-replicated
// B-reads missed L2 across XCDs (FETCH 593MB = 3x), half the waves idle.
// Cumulative R5-R9 lesson: any structure that (a) re-reads B per ot-tile or
// (b) barriers every 32-K-step lands at 165-230us.
// R10 breaks both invariants: ONE block owns all M for its 64-px B-panel
// (B fetched from HBM exactly once), full-K LDS staging (48KB), and exactly
// ONE barrier per block: phase1 = pure streaming (48 indep 256B loads/thread,
// like the 6.3TB/s copy kernel) + cvt + stats + swizzled ds_write; phase2 =
// pure MFMA, A-frags direct from L2-resident 288KB weights, no barriers.
// Swizzle: 16B chunk c ^= (row&7) on both ds_write and frag read (2-way max).
// ---------------------------------------------------------------------------

typedef unsigned short u16;
typedef unsigned int u32;
typedef short s16x8 __attribute__((ext_vector_type(8)));
typedef float f32x4 __attribute__((ext_vector_type(4)));

#define HW 16384
#define NB 8
#define CDIM 384
#define KVC 192

__device__ __forceinline__ float b2f(u16 u) {
  return __uint_as_float(((u32)u) << 16);
}
__device__ __forceinline__ u16 f2b(float f) {
  u32 u = __float_as_uint(f);
  u += 0x7fffu + ((u >> 16) & 1u);   // RNE
  return (u16)(u >> 16);
}
__device__ __forceinline__ u32 pack2(float a, float c) {
  return (u32)f2b(a) | ((u32)f2b(c) << 16);
}

// ---------------------------------------------------------------------------
// k0: fold LN weights into conv weights.  1024 threads.
// ---------------------------------------------------------------------------
__global__ void k0_prep(const float* __restrict__ wq, const float* __restrict__ wkv,
                        const float* __restrict__ wo,
                        const float* __restrict__ lnqw, const float* __restrict__ lnqb,
                        const float* __restrict__ lnkw, const float* __restrict__ lnkb,
                        u16* __restrict__ wqp, float* __restrict__ rwsQ, float* __restrict__ biasQ,
                        u16* __restrict__ wkvp, float* __restrict__ rwsKV, float* __restrict__ biasKV,
                        u16* __restrict__ wop) {
  int r = blockIdx.x * 256 + threadIdx.x;
  if (r < 384) {
    float rs = 0.f, bs = 0.f;
    for (int i = 0; i < 384; ++i) {
      float wp = wq[r * 384 + i] * lnqw[i];
      u16 h = f2b(wp);
      rs += b2f(h);
      bs += wq[r * 384 + i] * lnqb[i];
      wqp[r * 384 + i] = h;
    }
    rwsQ[r] = rs; biasQ[r] = bs;
  } else if (r < 640) {
    int o = r - 384;
    if (o < 192) {
      float rs = 0.f, bs = 0.f;
      for (int i = 0; i < 384; ++i) {
        float wp = wkv[o * 384 + i] * lnkw[i];
        u16 h = f2b(wp);
        rs += b2f(h);
        bs += wkv[o * 384 + i] * lnkb[i];
        wkvp[o * 384 + i] = h;
      }
      rwsKV[o] = rs; biasKV[o] = bs;
    } else {
      for (int i = 0; i < 384; ++i) wkvp[o * 384 + i] = 0;
      rwsKV[o] = 0.f; biasKV[o] = 0.f;
    }
  } else {
    int o = r - 640;
    for (int i = 0; i < 384; ++i) wop[o * 384 + i] = f2b(wo[o * 384 + i]);
  }
}

// ---------------------------------------------------------------------------
// gemm_fused: D[o][p] = sum_k A[o][k]*B[p][k], K=384, tile M x 64px,
// 512 thr (8 waves, WM x WN split, wave-tile (MF*16) x (NF*16)).
// Phase 1: stage B panel 64px x 384ch -> LDS (48KB), swizzled; MODE 0 from
//   f32 NCHW (+LN stats), MODE 1 from bf16 [p][384]. All loads independent.
// ONE __syncthreads(). Phase 2: 12 K-steps, A-frags DIRECT from global (L2),
//   B-frags from LDS, no barriers. LN epilogue (MODE 0) / f32 out (MODE 1).
// LDS chunk swizzle: 16B chunk index c stored at (c ^ (row&7)).
// ---------------------------------------------------------------------------
template <int MODE, int WM, int WN, int MF, int NF>
__global__ __launch_bounds__(512) void gemm_fused(const u16* __restrict__ A,
                                                  const void* __restrict__ Bsrc,
                                                  const float* __restrict__ rowsum,
                                                  const float* __restrict__ bias,
                                                  void* __restrict__ outv, int M) {
  __shared__ u16 tB[64 * 384];          // 48 KB, [row][swizzled 16B chunks]
  __shared__ float sredS[8][64], sredQ[8][64];
  __shared__ float muL[64], sdL[64];

  const int b = blockIdx.z, pt = blockIdx.x;
  const int tid = threadIdx.x;
  const int w = tid >> 6, l = tid & 63;
  const int wm = (WN == 1) ? w : (w >> 1);
  const int wn = (WN == 1) ? 0 : (w & 1);
  const int lr = l & 15, lg = l >> 4;

  f32x4 acc[MF][NF] = {};

  // ================= Phase 1: stage B panel =================
  if (MODE == 0) {
    const float* Bf = (const float*)Bsrc;
    const size_t fbase = (size_t)b * CDIM * HW + (size_t)pt * 64 + l;  // lane=px
    float s_ = 0.f, q_ = 0.f;
#pragma unroll
    for (int it = 0; it < 12; ++it) {
      float v[4];
#pragma unroll
      for (int j = 0; j < 4; ++j)
        v[j] = Bf[fbase + (size_t)(it * 32 + w * 4 + j) * HW];
#pragma unroll
      for (int j = 0; j < 4; ++j) { s_ += v[j]; q_ += v[j] * v[j]; }
      u32 lo = pack2(v[0], v[1]), hi = pack2(v[2], v[3]);
      int cidx = it * 4 + (w >> 1);                 // 16B chunk index (0..47)
      int off = l * 384 + ((cidx ^ (l & 7)) << 3) + (w & 1) * 4;  // u16 units
      *(uint2*)&tB[off] = make_uint2(lo, hi);
    }
    sredS[w][l] = s_;
    sredQ[w][l] = q_;
  } else {
    const u16* Bh = (const u16*)Bsrc;
#pragma unroll
    for (int i = 0; i < 6; ++i) {
      int chunk = tid + i * 512;                    // 0..3071
      int row = chunk / 48, c = chunk % 48;
      uint4 v = *(const uint4*)(Bh + ((size_t)(b * HW + pt * 64 + row)) * 384 + c * 8);
      *(uint4*)&tB[row * 384 + ((c ^ (row & 7)) << 3)] = v;
    }
  }
  __syncthreads();

  // LN stats combine (MODE 0)
  if (MODE == 0) {
    if (tid < 64) {
      float s = 0.f, q2 = 0.f;
#pragma unroll
      for (int g = 0; g < 8; ++g) { s += sredS[g][tid]; q2 += sredQ[g][tid]; }
      float mn = s * (1.f / 384.f);
      float var = q2 * (1.f / 384.f) - mn * mn;
      muL[tid] = mn;
      sdL[tid] = rsqrtf(var + 1e-5f);
    }
    __syncthreads();
  }

  // ================= Phase 2: MFMA, no barriers =================
#pragma unroll
  for (int ks = 0; ks < 12; ++ks) {
    const int ko = ks * 32 + lg * 8;                // u16 col
    const int cidx = ks * 4 + lg;                   // 16B chunk index
    s16x8 a[MF], bb[NF];
#pragma unroll
    for (int mf = 0; mf < MF; ++mf)
      a[mf] = *(const s16x8*)(A + (size_t)(wm * (MF * 16) + mf * 16 + lr) * 384 + ko);
#pragma unroll
    for (int nf = 0; nf < NF; ++nf) {
      int row = wn * (NF * 16) + nf * 16 + lr;
      bb[nf] = *(const s16x8*)&tB[row * 384 + ((cidx ^ (row & 7)) << 3)];
    }
#pragma unroll
    for (int mf = 0; mf < MF; ++mf)
#pragma unroll
      for (int nf = 0; nf < NF; ++nf)
        acc[mf][nf] = __builtin_amdgcn_mfma_f32_16x16x32_bf16(a[mf], bb[nf], acc[mf][nf], 0, 0, 0);
  }

  // ================= Epilogue =================
#pragma unroll
  for (int nf = 0; nf < NF; ++nf) {
    int row = wn * (NF * 16) + nf * 16 + lr;
    int p = pt * 64 + row;
    float m_ = 0.f, s_ = 0.f;
    if (MODE == 0) { m_ = muL[row]; s_ = sdL[row]; }
#pragma unroll
    for (int mf = 0; mf < MF; ++mf) {
#pragma unroll
      for (int r = 0; r < 4; ++r) {
        int o = wm * (MF * 16) + mf * 16 + lg * 4 + r;
        if (MODE == 0) {
          float v = s_ * (acc[mf][nf][r] - m_ * rowsum[o]) + bias[o];
          ((u16*)outv)[((size_t)(b * M + o)) * HW + p] = f2b(v);
        } else {
          ((float*)outv)[((size_t)(b * CDIM + o)) * HW + p] = acc[mf][nf][r];
        }
      }
    }
  }
}

// ---------------------------------------------------------------------------
// k4: depthwise 3x3 (zero pad), LDS-staged plane + fused row l2-norm.
// ---------------------------------------------------------------------------
__global__ __launch_bounds__(256) void k4_dw(const u16* __restrict__ qp, const u16* __restrict__ kvp,
                                             const float* __restrict__ wqdw, const float* __restrict__ wkvdw,
                                             u16* __restrict__ qd, u16* __restrict__ kvd,
                                             float* __restrict__ rnq, float* __restrict__ rnk) {
  __shared__ u16 plane[16384];     // 32 KB
  __shared__ float red[256];

  int c = blockIdx.x, b = blockIdx.y;
  int tid = threadIdx.x;
  const u16* in; u16* outb; const float* wp; int C;
  int isQ = (c < 384), cc = isQ ? c : c - 384;
  if (isQ) { in = qp; outb = qd; wp = wqdw + cc * 9; C = CDIM; }
  else     { in = kvp; outb = kvd; wp = wkvdw + cc * 9; C = KVC; }
  size_t base = ((size_t)(b * C + cc)) * HW;

  float w[9];
#pragma unroll
  for (int j = 0; j < 9; ++j) w[j] = wp[j];

  const uint4* gsrc = (const uint4*)(in + base);
  uint4* lplane = (uint4*)plane;
#pragma unroll
  for (int i = 0; i < 8; ++i) lplane[tid + i * 256] = gsrc[tid + i * 256];
  __syncthreads();

  uint4* gdst = (uint4*)(outb + base);
  float ns = 0.f;
#pragma unroll
  for (int it = 0; it < 8; ++it) {
    int idx = tid + it * 256;
    int y = idx >> 4, ox = idx & 15;
    int x0 = ox * 8;

    float r[3][10];
#pragma unroll
    for (int rr = 0; rr < 3; ++rr) {
      int yy = y + rr - 1;
      if ((unsigned)yy < 128u) {
        int rbase = yy * 128 + x0;
        r[rr][0] = (x0 > 0) ? b2f(plane[rbase - 1]) : 0.f;
        uint4 v = *(const uint4*)&plane[rbase];
        u32 ws[4] = {v.x, v.y, v.z, v.w};
#pragma unroll
        for (int j = 0; j < 4; ++j) {
          r[rr][1 + 2 * j] = b2f((u16)(ws[j] & 0xffff));
          r[rr][2 + 2 * j] = b2f((u16)(ws[j] >> 16));
        }
        r[rr][9] = (x0 < 120) ? b2f(plane[rbase + 8]) : 0.f;
      } else {
#pragma unroll
        for (int j = 0; j < 10; ++j) r[rr][j] = 0.f;
      }
    }

    u32 packed[4];
#pragma unroll
    for (int j = 0; j < 8; ++j) {
      float a = 0.f;
#pragma unroll
      for (int rr = 0; rr < 3; ++rr)
#pragma unroll
        for (int dx = 0; dx < 3; ++dx)
          a += w[rr * 3 + dx] * r[rr][j + dx];
      u16 h = f2b(a);
      float hv = b2f(h);
      ns += hv * hv;
      if (j & 1) packed[j >> 1] |= ((u32)h) << 16; else packed[j >> 1] = (u32)h;
    }
    gdst[idx] = make_uint4(packed[0], packed[1], packed[2], packed[3]);
  }

  red[tid] = ns;
  __syncthreads();
  for (int st = 128; st > 0; st >>= 1) {
    if (tid < st) red[tid] += red[tid + st];
    __syncthreads();
  }
  if (tid == 0) {
    float n = sqrtf(red[0]);
    float inv = 1.f / fmaxf(n, 1e-12f);
    if (isQ) rnq[b * 384 + cc] = inv;
    else if (cc < 96) rnk[b * 96 + cc] = inv;
  }
}

// ---------------------------------------------------------------------------
// k5b: transpose v (kvd rows 96..191) -> vt [b][p][96] bf16. grid (64, 8).
// ---------------------------------------------------------------------------
__global__ void k5b_vt(const u16* __restrict__ kvd, u16* __restrict__ vt) {
  int p = blockIdx.x * 256 + threadIdx.x;
  int b = blockIdx.y;
  size_t sb = ((size_t)(b * KVC + 96)) * HW + p;
  uint4* dv = (uint4*)vt + ((size_t)(b * HW + p)) * 12;
  for (int j8 = 0; j8 < 12; ++j8) {
    u32 w[4];
#pragma unroll
    for (int j = 0; j < 8; ++j) {
      u16 h = kvd[sb + (size_t)(j8 * 8 + j) * HW];
      if (j & 1) w[j >> 1] |= ((u32)h) << 16; else w[j >> 1] = (u32)h;
    }
    dv[j8] = make_uint4(w[0], w[1], w[2], w[3]);
  }
}

// ---------------------------------------------------------------------------
// k6: split-K QK^T partials. grid (16, 8, 8).
// ---------------------------------------------------------------------------
__global__ __launch_bounds__(256) void k6_qk(const u16* __restrict__ qd,
                                             const u16* __restrict__ kvd,
                                             float* __restrict__ spart) {
  int kc = blockIdx.x, h = blockIdx.y, b = blockIdx.z;
  int tid = threadIdx.x;
  int w = tid >> 6, l = tid & 63, lr = l & 15, lg = l >> 4;
  int g = h >> 2;
  int p0 = kc * 1024 + w * 256;

  f32x4 acc[3][3] = {};
  size_t qbase = ((size_t)(b * CDIM + h * 48 + lr)) * HW;
  size_t kbase = ((size_t)(b * KVC + g * 48 + lr)) * HW;

  for (int ks = 0; ks < 8; ++ks) {
    int pp = p0 + ks * 32 + lg * 8;
    s16x8 a[3], bb[3];
#pragma unroll
    for (int mi = 0; mi < 3; ++mi) a[mi] = *(const s16x8*)(qd + qbase + (size_t)mi * 16 * HW + pp);
#pragma unroll
    for (int ni = 0; ni < 3; ++ni) bb[ni] = *(const s16x8*)(kvd + kbase + (size_t)ni * 16 * HW + pp);
#pragma unroll
    for (int mi = 0; mi < 3; ++mi)
#pragma unroll
      for (int ni = 0; ni < 3; ++ni)
        acc[mi][ni] = __builtin_amdgcn_mfma_f32_16x16x32_bf16(a[mi], bb[ni], acc[mi][ni], 0, 0, 0);
  }

  size_t sb = ((size_t)((((b * 8 + h) * 16) + kc) * 4 + w)) * 2304;
#pragma unroll
  for (int mi = 0; mi < 3; ++mi)
#pragma unroll
    for (int ni = 0; ni < 3; ++ni)
#pragma unroll
      for (int r = 0; r < 4; ++r) {
        int c = mi * 16 + lg * 4 + r, d = ni * 16 + lr;
        spart[sb + c * 48 + d] = acc[mi][ni][r];
      }
}

// ---------------------------------------------------------------------------
// k7: reduce partials + scale + softmax -> P~ [b][384][96] bf16.
// ---------------------------------------------------------------------------
__global__ void k7_sm(const float* __restrict__ spart, const float* __restrict__ temp,
                      const float* __restrict__ rnq, const float* __restrict__ rnk,
                      u16* __restrict__ ptil) {
  int h = blockIdx.x, b = blockIdx.y, tid = threadIdx.x;
  int g = h >> 2;
  __shared__ float S[2304];
  size_t base = ((size_t)((b * 8 + h) * 64)) * 2304;
  for (int e = tid; e < 2304; e += 64) {
    float s = 0.f;
    for (int j = 0; j < 64; ++j) s += spart[base + (size_t)j * 2304 + e];
    S[e] = s;
  }
  __syncthreads();
  if (tid < 48) {
    int c = tid;
    float sq = temp[h] * rnq[b * 384 + h * 48 + c];
    float mx = -1e30f;
    for (int d = 0; d < 48; ++d) {
      float v = S[c * 48 + d] * sq * rnk[b * 96 + g * 48 + d];
      mx = fmaxf(mx, v);
    }
    float sum = 0.f;
    for (int d = 0; d < 48; ++d) {
      float v = S[c * 48 + d] * sq * rnk[b * 96 + g * 48 + d];
      sum += __expf(v - mx);
    }
    float inv = 1.f / sum;
    u16* row = ptil + ((size_t)(b * 384 + h * 48 + c)) * 96;
    for (int dk = 0; dk < 96; ++dk) {
      int d = dk - g * 48;
      float pv = 0.f;
      if (d >= 0 && d < 48) {
        float v = S[c * 48 + d] * sq * rnk[b * 96 + g * 48 + d];
        pv = __expf(v - mx) * inv;
      }
      row[dk] = f2b(pv);
    }
  }
}

// ---------------------------------------------------------------------------
// k8: Yt[p][c] = sum_dk vt[p][dk] * P~[c][dk].  grid (128, 8), 512 thr.
// ---------------------------------------------------------------------------
__global__ __launch_bounds__(512) void k8_pv(const u16* __restrict__ vt,
                                             const u16* __restrict__ ptil,
                                             u16* __restrict__ yt) {
  int ptb = blockIdx.x, b = blockIdx.y;
  int tid = threadIdx.x;
  int w = tid >> 6, l = tid & 63, lr = l & 15, lg = l >> 4;
  int wm = w >> 2, wn = w & 3;

  f32x4 acc[4][6] = {};
  size_t arow0 = ((size_t)(b * HW + ptb * 128 + wm * 64 + lr)) * 96;
  size_t brow0 = ((size_t)(b * CDIM + wn * 96 + lr)) * 96;

  for (int ks = 0; ks < 3; ++ks) {
    int ko = ks * 32 + lg * 8;
    s16x8 a[4], bb[6];
#pragma unroll
    for (int mf = 0; mf < 4; ++mf) a[mf] = *(const s16x8*)(vt + arow0 + (size_t)mf * 16 * 96 + ko);
#pragma unroll
    for (int nf = 0; nf < 6; ++nf) bb[nf] = *(const s16x8*)(ptil + brow0 + (size_t)nf * 16 * 96 + ko);
#pragma unroll
    for (int mf = 0; mf < 4; ++mf)
#pragma unroll
      for (int nf = 0; nf < 6; ++nf)
        acc[mf][nf] = __builtin_amdgcn_mfma_f32_16x16x32_bf16(a[mf], bb[nf], acc[mf][nf], 0, 0, 0);
  }

#pragma unroll
  for (int mf = 0; mf < 4; ++mf)
#pragma unroll
    for (int nf = 0; nf < 6; ++nf)
#pragma unroll
      for (int r = 0; r < 4; ++r) {
        int p = ptb * 128 + wm * 64 + mf * 16 + lg * 4 + r;
        int c = wn * 96 + nf * 16 + lr;
        yt[((size_t)(b * HW + p)) * 384 + c] = f2b(acc[mf][nf][r]);
      }
}

// ---------------------------------------------------------------------------
extern "C" void kernel_launch(void* const* d_in, const int* in_sizes, int n_in,
                              void* d_out, int out_size, void* d_ws, size_t ws_size,
                              hipStream_t stream) {
  const float* q    = (const float*)d_in[0];
  const float* k    = (const float*)d_in[1];
  const float* w_q  = (const float*)d_in[2];
  const float* w_kv = (const float*)d_in[3];
  const float* w_qd = (const float*)d_in[4];
  const float* w_kd = (const float*)d_in[5];
  const float* w_o  = (const float*)d_in[6];
  const float* temp = (const float*)d_in[7];
  const float* lnqw = (const float*)d_in[8];
  const float* lnqb = (const float*)d_in[9];
  const float* lnkw = (const float*)d_in[10];
  const float* lnkb = (const float*)d_in[11];
  float* out = (float*)d_out;

  char* ws = (char*)d_ws;
  size_t off = 0;
  auto alloc = [&](size_t bytes) -> void* {
    void* p = ws + off;
    off += (bytes + 255) & ~(size_t)255;
    return p;
  };

  u16*   wqp   = (u16*)alloc(384 * 384 * 2);
  float* rwsQ  = (float*)alloc(384 * 4);
  float* biasQ = (float*)alloc(384 * 4);
  u16*   wkvp  = (u16*)alloc(256 * 384 * 2);   // padded to 256 rows
  float* rwsKV = (float*)alloc(256 * 4);
  float* biasKV= (float*)alloc(256 * 4);
  u16*   wop   = (u16*)alloc(384 * 384 * 2);
  u16*   qp    = (u16*)alloc((size_t)NB * CDIM * HW * 2);  // aliased as yt later
  u16*   kvp   = (u16*)alloc((size_t)NB * KVC * HW * 2);
  u16*   qd    = (u16*)alloc((size_t)NB * CDIM * HW * 2);
  u16*   kvd   = (u16*)alloc((size_t)NB * KVC * HW * 2);
  u16*   vt    = (u16*)alloc((size_t)NB * HW * 96 * 2);
  float* spart = (float*)alloc((size_t)4096 * 2304 * 4);
  u16*   ptil  = (u16*)alloc((size_t)NB * CDIM * 96 * 2);
  float* rnq   = (float*)alloc((size_t)NB * 384 * 4);
  float* rnk   = (float*)alloc((size_t)NB * 96 * 4);

  // lifetime alias (sequential stream => safe): qp dead after k4
  u16* yt = qp;

  k0_prep<<<4, 256, 0, stream>>>(w_q, w_kv, w_o, lnqw, lnqb, lnkw, lnkb,
                                 wqp, rwsQ, biasQ, wkvp, rwsKV, biasKV, wop);

  // B fetched exactly once per pixel: one block owns all M for its 64-px panel
  gemm_fused<0, 8, 1, 3, 4><<<dim3(256, 1, NB), 512, 0, stream>>>(wqp, q, rwsQ, biasQ, qp, 384);
  gemm_fused<0, 4, 2, 3, 2><<<dim3(256, 1, NB), 512, 0, stream>>>(wkvp, k, rwsKV, biasKV, kvp, 192);

  k4_dw<<<dim3(576, NB), 256, 0, stream>>>(qp, kvp, w_qd, w_kd, qd, kvd, rnq, rnk);

  k5b_vt<<<dim3(64, NB), 256, 0, stream>>>(kvd, vt);

  k6_qk<<<dim3(16, 8, NB), 256, 0, stream>>>(qd, kvd, spart);
  k7_sm<<<dim3(8, NB), 64, 0, stream>>>(spart, temp, rnq, rnk, ptil);

  k8_pv<<<dim3(128, NB), 512, 0, stream>>>(vt, ptil, yt);

  gemm_fused<1, 8, 1, 3, 4><<<dim3(256, 1, NB), 512, 0, stream>>>(wop, yt, nullptr, nullptr, out, 384);
}

// Round 11
// 628.188 us; speedup vs baseline: 2.1845x; 1.0030x over previous
//
#include <hip/hip_runtime.h>
#include <math.h>

// ---------------------------------------------------------------------------
// CrossGroupedQueryAttention on MI355X — round 11
//
// R10 post-mortem: traffic now ideal (FETCH 107MB, WRITE 98MB) but still
// 1.24 TB/s effective. Cross-round invariant (R4-R10, six structures, all
// 165-230us): the epilogue write pattern never changed — 32B (bf16) / 64B
// (f32) segments scattered at 64KB plane stride, consecutive pt on different
// XCDs. That sub-line scatter IS the ~165us floor.
// R11 (structure unchanged from R10): (1) epilogue via LDS transpose ->
// 128B/256B contiguous segments per store instr; (2) XCD-bijective pt
// swizzle so same-XCD blocks cover contiguous px windows (L2 write merge +
// DRAM page locality on reads).
// ---------------------------------------------------------------------------

typedef unsigned short u16;
typedef unsigned int u32;
typedef short s16x8 __attribute__((ext_vector_type(8)));
typedef float f32x4 __attribute__((ext_vector_type(4)));

#define HW 16384
#define NB 8
#define CDIM 384
#define KVC 192

__device__ __forceinline__ float b2f(u16 u) {
  return __uint_as_float(((u32)u) << 16);
}
__device__ __forceinline__ u16 f2b(float f) {
  u32 u = __float_as_uint(f);
  u += 0x7fffu + ((u >> 16) & 1u);   // RNE
  return (u16)(u >> 16);
}
__device__ __forceinline__ u32 pack2(float a, float c) {
  return (u32)f2b(a) | ((u32)f2b(c) << 16);
}

// ---------------------------------------------------------------------------
// k0: fold LN weights into conv weights.  1024 threads.
// ---------------------------------------------------------------------------
__global__ void k0_prep(const float* __restrict__ wq, const float* __restrict__ wkv,
                        const float* __restrict__ wo,
                        const float* __restrict__ lnqw, const float* __restrict__ lnqb,
                        const float* __restrict__ lnkw, const float* __restrict__ lnkb,
                        u16* __restrict__ wqp, float* __restrict__ rwsQ, float* __restrict__ biasQ,
                        u16* __restrict__ wkvp, float* __restrict__ rwsKV, float* __restrict__ biasKV,
                        u16* __restrict__ wop) {
  int r = blockIdx.x * 256 + threadIdx.x;
  if (r < 384) {
    float rs = 0.f, bs = 0.f;
    for (int i = 0; i < 384; ++i) {
      float wp = wq[r * 384 + i] * lnqw[i];
      u16 h = f2b(wp);
      rs += b2f(h);
      bs += wq[r * 384 + i] * lnqb[i];
      wqp[r * 384 + i] = h;
    }
    rwsQ[r] = rs; biasQ[r] = bs;
  } else if (r < 640) {
    int o = r - 384;
    if (o < 192) {
      float rs = 0.f, bs = 0.f;
      for (int i = 0; i < 384; ++i) {
        float wp = wkv[o * 384 + i] * lnkw[i];
        u16 h = f2b(wp);
        rs += b2f(h);
        bs += wkv[o * 384 + i] * lnkb[i];
        wkvp[o * 384 + i] = h;
      }
      rwsKV[o] = rs; biasKV[o] = bs;
    } else {
      for (int i = 0; i < 384; ++i) wkvp[o * 384 + i] = 0;
      rwsKV[o] = 0.f; biasKV[o] = 0.f;
    }
  } else {
    int o = r - 640;
    for (int i = 0; i < 384; ++i) wop[o * 384 + i] = f2b(wo[o * 384 + i]);
  }
}

// ---------------------------------------------------------------------------
// gemm_fused: D[o][p] = sum_k A[o][k]*B[p][k], K=384, tile M x 64px,
// 512 thr (8 waves, WM x WN, wave-tile (MF*16) x (NF*16)). R10 structure:
// phase1 stage B panel (48KB LDS) + LN stats, ONE barrier, phase2 pure MFMA
// (A direct from L2). NEW: epilogue via LDS transpose -> 128B (bf16) /
// 256B (f32) contiguous write segments; pt is XCD-swizzled by caller.
// smem aliasing: [0,49152) tB (phases) -> epilogue dump buffer; 
// [49152,53248) sredS; [53248,57344) sredQ. muL/sdL separate (live in epi).
// ---------------------------------------------------------------------------
template <int MODE, int WM, int WN, int MF, int NF>
__global__ __launch_bounds__(512) void gemm_fused(const u16* __restrict__ A,
                                                  const void* __restrict__ Bsrc,
                                                  const float* __restrict__ rowsum,
                                                  const float* __restrict__ bias,
                                                  void* __restrict__ outv, int M) {
  __shared__ __align__(16) char smem[57344];
  u16*   tB    = (u16*)smem;                  // 64 x 384 u16 = 48 KB
  float* sredS = (float*)(smem + 49152);      // [8][64]
  float* sredQ = (float*)(smem + 53248);      // [8][64]
  u16*   chB16 = (u16*)smem;                  // epilogue: [M_TILE][72] u16
  float* chB32 = (float*)smem;                // epilogue: [192][72] f32
  __shared__ float muL[64], sdL[64];

  constexpr int M_TILE = WM * MF * 16;

  const int b = blockIdx.z;
  const int pt = ((blockIdx.x & 7) << 5) | (blockIdx.x >> 3);   // XCD-bijective
  const int tid = threadIdx.x;
  const int w = tid >> 6, l = tid & 63;
  const int wm = (WN == 1) ? w : (w >> 1);
  const int wn = (WN == 1) ? 0 : (w & 1);
  const int lr = l & 15, lg = l >> 4;

  f32x4 acc[MF][NF] = {};

  // ================= Phase 1: stage B panel =================
  if (MODE == 0) {
    const float* Bf = (const float*)Bsrc;
    const size_t fbase = (size_t)b * CDIM * HW + (size_t)pt * 64 + l;  // lane=px
    float s_ = 0.f, q_ = 0.f;
#pragma unroll
    for (int it = 0; it < 12; ++it) {
      float v[4];
#pragma unroll
      for (int j = 0; j < 4; ++j)
        v[j] = Bf[fbase + (size_t)(it * 32 + w * 4 + j) * HW];
#pragma unroll
      for (int j = 0; j < 4; ++j) { s_ += v[j]; q_ += v[j] * v[j]; }
      u32 lo = pack2(v[0], v[1]), hi = pack2(v[2], v[3]);
      int cidx = it * 4 + (w >> 1);                 // 16B chunk index (0..47)
      int off = l * 384 + ((cidx ^ (l & 7)) << 3) + (w & 1) * 4;  // u16 units
      *(uint2*)&tB[off] = make_uint2(lo, hi);
    }
    sredS[w * 64 + l] = s_;
    sredQ[w * 64 + l] = q_;
  } else {
    const u16* Bh = (const u16*)Bsrc;
#pragma unroll
    for (int i = 0; i < 6; ++i) {
      int chunk = tid + i * 512;                    // 0..3071
      int row = chunk / 48, c = chunk % 48;
      uint4 v = *(const uint4*)(Bh + ((size_t)(b * HW + pt * 64 + row)) * 384 + c * 8);
      *(uint4*)&tB[row * 384 + ((c ^ (row & 7)) << 3)] = v;
    }
  }
  __syncthreads();

  // LN stats combine (MODE 0)
  if (MODE == 0) {
    if (tid < 64) {
      float s = 0.f, q2 = 0.f;
#pragma unroll
      for (int g = 0; g < 8; ++g) { s += sredS[g * 64 + tid]; q2 += sredQ[g * 64 + tid]; }
      float mn = s * (1.f / 384.f);
      float var = q2 * (1.f / 384.f) - mn * mn;
      muL[tid] = mn;
      sdL[tid] = rsqrtf(var + 1e-5f);
    }
    __syncthreads();
  }

  // ================= Phase 2: MFMA, no barriers =================
#pragma unroll
  for (int ks = 0; ks < 12; ++ks) {
    const int ko = ks * 32 + lg * 8;                // u16 col
    const int cidx = ks * 4 + lg;                   // 16B chunk index
    s16x8 a[MF], bb[NF];
#pragma unroll
    for (int mf = 0; mf < MF; ++mf)
      a[mf] = *(const s16x8*)(A + (size_t)(wm * (MF * 16) + mf * 16 + lr) * 384 + ko);
#pragma unroll
    for (int nf = 0; nf < NF; ++nf) {
      int row = wn * (NF * 16) + nf * 16 + lr;
      bb[nf] = *(const s16x8*)&tB[row * 384 + ((cidx ^ (row & 7)) << 3)];
    }
#pragma unroll
    for (int mf = 0; mf < MF; ++mf)
#pragma unroll
      for (int nf = 0; nf < NF; ++nf)
        acc[mf][nf] = __builtin_amdgcn_mfma_f32_16x16x32_bf16(a[mf], bb[nf], acc[mf][nf], 0, 0, 0);
  }

  // ================= Epilogue: LDS transpose -> coalesced stores ==========
  if (MODE == 0) {
    __syncthreads();                           // tB reads done; reuse as chB16
#pragma unroll
    for (int nf = 0; nf < NF; ++nf) {
      int prow = wn * (NF * 16) + nf * 16 + lr;          // pixel 0..63
      float m_ = muL[prow], s_ = sdL[prow];
#pragma unroll
      for (int mf = 0; mf < MF; ++mf)
#pragma unroll
        for (int r = 0; r < 4; ++r) {
          int orow = wm * (MF * 16) + mf * 16 + lg * 4 + r;
          float v = s_ * (acc[mf][nf][r] - m_ * rowsum[orow]) + bias[orow];
          chB16[orow * 72 + prow] = f2b(v);
        }
    }
    __syncthreads();
    // store: each uint4 = 8px x bf16; instr = 8 rows x 128B segments
    const int total = M_TILE * 8;
    for (int i = tid; i < total; i += 512) {
      int row = i >> 3, c8 = i & 7;
      uint4 v = *(const uint4*)&chB16[row * 72 + c8 * 8];
      *(uint4*)((u16*)outv + ((size_t)(b * M + row)) * HW + pt * 64 + c8 * 8) = v;
    }
  } else {
    // f32 out, 384 rows in 2 chunks of 192 (55 KB each)
#pragma unroll
    for (int cc = 0; cc < 2; ++cc) {
      __syncthreads();                         // protect prev reads / tB
      if ((wm >> 2) == cc) {
#pragma unroll
        for (int nf = 0; nf < NF; ++nf) {
          int prow = wn * (NF * 16) + nf * 16 + lr;
#pragma unroll
          for (int mf = 0; mf < MF; ++mf)
#pragma unroll
            for (int r = 0; r < 4; ++r) {
              int orow_l = (wm & 3) * (MF * 16) + mf * 16 + lg * 4 + r;
              chB32[orow_l * 72 + prow] = acc[mf][nf][r];
            }
        }
      }
      __syncthreads();
      // store: uint4 = 4px f32; instr = 4 rows x 256B segments
      for (int i = tid; i < 192 * 16; i += 512) {
        int row = i >> 4, c4 = i & 15;
        uint4 v = *(const uint4*)&chB32[row * 72 + c4 * 4];
        *(uint4*)((float*)outv + ((size_t)(b * CDIM + cc * 192 + row)) * HW + pt * 64 + c4 * 4) = v;
      }
    }
  }
}

// ---------------------------------------------------------------------------
// k4: depthwise 3x3 (zero pad), LDS-staged plane + fused row l2-norm.
// ---------------------------------------------------------------------------
__global__ __launch_bounds__(256) void k4_dw(const u16* __restrict__ qp, const u16* __restrict__ kvp,
                                             const float* __restrict__ wqdw, const float* __restrict__ wkvdw,
                                             u16* __restrict__ qd, u16* __restrict__ kvd,
                                             float* __restrict__ rnq, float* __restrict__ rnk) {
  __shared__ u16 plane[16384];     // 32 KB
  __shared__ float red[256];

  int c = blockIdx.x, b = blockIdx.y;
  int tid = threadIdx.x;
  const u16* in; u16* outb; const float* wp; int C;
  int isQ = (c < 384), cc = isQ ? c : c - 384;
  if (isQ) { in = qp; outb = qd; wp = wqdw + cc * 9; C = CDIM; }
  else     { in = kvp; outb = kvd; wp = wkvdw + cc * 9; C = KVC; }
  size_t base = ((size_t)(b * C + cc)) * HW;

  float w[9];
#pragma unroll
  for (int j = 0; j < 9; ++j) w[j] = wp[j];

  const uint4* gsrc = (const uint4*)(in + base);
  uint4* lplane = (uint4*)plane;
#pragma unroll
  for (int i = 0; i < 8; ++i) lplane[tid + i * 256] = gsrc[tid + i * 256];
  __syncthreads();

  uint4* gdst = (uint4*)(outb + base);
  float ns = 0.f;
#pragma unroll
  for (int it = 0; it < 8; ++it) {
    int idx = tid + it * 256;
    int y = idx >> 4, ox = idx & 15;
    int x0 = ox * 8;

    float r[3][10];
#pragma unroll
    for (int rr = 0; rr < 3; ++rr) {
      int yy = y + rr - 1;
      if ((unsigned)yy < 128u) {
        int rbase = yy * 128 + x0;
        r[rr][0] = (x0 > 0) ? b2f(plane[rbase - 1]) : 0.f;
        uint4 v = *(const uint4*)&plane[rbase];
        u32 ws[4] = {v.x, v.y, v.z, v.w};
#pragma unroll
        for (int j = 0; j < 4; ++j) {
          r[rr][1 + 2 * j] = b2f((u16)(ws[j] & 0xffff));
          r[rr][2 + 2 * j] = b2f((u16)(ws[j] >> 16));
        }
        r[rr][9] = (x0 < 120) ? b2f(plane[rbase + 8]) : 0.f;
      } else {
#pragma unroll
        for (int j = 0; j < 10; ++j) r[rr][j] = 0.f;
      }
    }

    u32 packed[4];
#pragma unroll
    for (int j = 0; j < 8; ++j) {
      float a = 0.f;
#pragma unroll
      for (int rr = 0; rr < 3; ++rr)
#pragma unroll
        for (int dx = 0; dx < 3; ++dx)
          a += w[rr * 3 + dx] * r[rr][j + dx];
      u16 h = f2b(a);
      float hv = b2f(h);
      ns += hv * hv;
      if (j & 1) packed[j >> 1] |= ((u32)h) << 16; else packed[j >> 1] = (u32)h;
    }
    gdst[idx] = make_uint4(packed[0], packed[1], packed[2], packed[3]);
  }

  red[tid] = ns;
  __syncthreads();
  for (int st = 128; st > 0; st >>= 1) {
    if (tid < st) red[tid] += red[tid + st];
    __syncthreads();
  }
  if (tid == 0) {
    float n = sqrtf(red[0]);
    float inv = 1.f / fmaxf(n, 1e-12f);
    if (isQ) rnq[b * 384 + cc] = inv;
    else if (cc < 96) rnk[b * 96 + cc] = inv;
  }
}

// ---------------------------------------------------------------------------
// k5b: transpose v (kvd rows 96..191) -> vt [b][p][96] bf16. grid (64, 8).
// ---------------------------------------------------------------------------
__global__ void k5b_vt(const u16* __restrict__ kvd, u16* __restrict__ vt) {
  int p = blockIdx.x * 256 + threadIdx.x;
  int b = blockIdx.y;
  size_t sb = ((size_t)(b * KVC + 96)) * HW + p;
  uint4* dv = (uint4*)vt + ((size_t)(b * HW + p)) * 12;
  for (int j8 = 0; j8 < 12; ++j8) {
    u32 w[4];
#pragma unroll
    for (int j = 0; j < 8; ++j) {
      u16 h = kvd[sb + (size_t)(j8 * 8 + j) * HW];
      if (j & 1) w[j >> 1] |= ((u32)h) << 16; else w[j >> 1] = (u32)h;
    }
    dv[j8] = make_uint4(w[0], w[1], w[2], w[3]);
  }
}

// ---------------------------------------------------------------------------
// k6: split-K QK^T partials. grid (16, 8, 8).
// ---------------------------------------------------------------------------
__global__ __launch_bounds__(256) void k6_qk(const u16* __restrict__ qd,
                                             const u16* __restrict__ kvd,
                                             float* __restrict__ spart) {
  int kc = blockIdx.x, h = blockIdx.y, b = blockIdx.z;
  int tid = threadIdx.x;
  int w = tid >> 6, l = tid & 63, lr = l & 15, lg = l >> 4;
  int g = h >> 2;
  int p0 = kc * 1024 + w * 256;

  f32x4 acc[3][3] = {};
  size_t qbase = ((size_t)(b * CDIM + h * 48 + lr)) * HW;
  size_t kbase = ((size_t)(b * KVC + g * 48 + lr)) * HW;

  for (int ks = 0; ks < 8; ++ks) {
    int pp = p0 + ks * 32 + lg * 8;
    s16x8 a[3], bb[3];
#pragma unroll
    for (int mi = 0; mi < 3; ++mi) a[mi] = *(const s16x8*)(qd + qbase + (size_t)mi * 16 * HW + pp);
#pragma unroll
    for (int ni = 0; ni < 3; ++ni) bb[ni] = *(const s16x8*)(kvd + kbase + (size_t)ni * 16 * HW + pp);
#pragma unroll
    for (int mi = 0; mi < 3; ++mi)
#pragma unroll
      for (int ni = 0; ni < 3; ++ni)
        acc[mi][ni] = __builtin_amdgcn_mfma_f32_16x16x32_bf16(a[mi], bb[ni], acc[mi][ni], 0, 0, 0);
  }

  size_t sb = ((size_t)((((b * 8 + h) * 16) + kc) * 4 + w)) * 2304;
#pragma unroll
  for (int mi = 0; mi < 3; ++mi)
#pragma unroll
    for (int ni = 0; ni < 3; ++ni)
#pragma unroll
      for (int r = 0; r < 4; ++r) {
        int c = mi * 16 + lg * 4 + r, d = ni * 16 + lr;
        spart[sb + c * 48 + d] = acc[mi][ni][r];
      }
}

// ---------------------------------------------------------------------------
// k7: reduce partials + scale + softmax -> P~ [b][384][96] bf16.
// ---------------------------------------------------------------------------
__global__ void k7_sm(const float* __restrict__ spart, const float* __restrict__ temp,
                      const float* __restrict__ rnq, const float* __restrict__ rnk,
                      u16* __restrict__ ptil) {
  int h = blockIdx.x, b = blockIdx.y, tid = threadIdx.x;
  int g = h >> 2;
  __shared__ float S[2304];
  size_t base = ((size_t)((b * 8 + h) * 64)) * 2304;
  for (int e = tid; e < 2304; e += 64) {
    float s = 0.f;
    for (int j = 0; j < 64; ++j) s += spart[base + (size_t)j * 2304 + e];
    S[e] = s;
  }
  __syncthreads();
  if (tid < 48) {
    int c = tid;
    float sq = temp[h] * rnq[b * 384 + h * 48 + c];
    float mx = -1e30f;
    for (int d = 0; d < 48; ++d) {
      float v = S[c * 48 + d] * sq * rnk[b * 96 + g * 48 + d];
      mx = fmaxf(mx, v);
    }
    float sum = 0.f;
    for (int d = 0; d < 48; ++d) {
      float v = S[c * 48 + d] * sq * rnk[b * 96 + g * 48 + d];
      sum += __expf(v - mx);
    }
    float inv = 1.f / sum;
    u16* row = ptil + ((size_t)(b * 384 + h * 48 + c)) * 96;
    for (int dk = 0; dk < 96; ++dk) {
      int d = dk - g * 48;
      float pv = 0.f;
      if (d >= 0 && d < 48) {
        float v = S[c * 48 + d] * sq * rnk[b * 96 + g * 48 + d];
        pv = __expf(v - mx) * inv;
      }
      row[dk] = f2b(pv);
    }
  }
}

// ---------------------------------------------------------------------------
// k8: Yt[p][c] = sum_dk vt[p][dk] * P~[c][dk].  grid (128, 8), 512 thr.
// ---------------------------------------------------------------------------
__global__ __launch_bounds__(512) void k8_pv(const u16* __restrict__ vt,
                                             const u16* __restrict__ ptil,
                                             u16* __restrict__ yt) {
  int ptb = blockIdx.x, b = blockIdx.y;
  int tid = threadIdx.x;
  int w = tid >> 6, l = tid & 63, lr = l & 15, lg = l >> 4;
  int wm = w >> 2, wn = w & 3;

  f32x4 acc[4][6] = {};
  size_t arow0 = ((size_t)(b * HW + ptb * 128 + wm * 64 + lr)) * 96;
  size_t brow0 = ((size_t)(b * CDIM + wn * 96 + lr)) * 96;

  for (int ks = 0; ks < 3; ++ks) {
    int ko = ks * 32 + lg * 8;
    s16x8 a[4], bb[6];
#pragma unroll
    for (int mf = 0; mf < 4; ++mf) a[mf] = *(const s16x8*)(vt + arow0 + (size_t)mf * 16 * 96 + ko);
#pragma unroll
    for (int nf = 0; nf < 6; ++nf) bb[nf] = *(const s16x8*)(ptil + brow0 + (size_t)nf * 16 * 96 + ko);
#pragma unroll
    for (int mf = 0; mf < 4; ++mf)
#pragma unroll
      for (int nf = 0; nf < 6; ++nf)
        acc[mf][nf] = __builtin_amdgcn_mfma_f32_16x16x32_bf16(a[mf], bb[nf], acc[mf][nf], 0, 0, 0);
  }

#pragma unroll
  for (int mf = 0; mf < 4; ++mf)
#pragma unroll
    for (int nf = 0; nf < 6; ++nf)
#pragma unroll
      for (int r = 0; r < 4; ++r) {
        int p = ptb * 128 + wm * 64 + mf * 16 + lg * 4 + r;
        int c = wn * 96 + nf * 16 + lr;
        yt[((size_t)(b * HW + p)) * 384 + c] = f2b(acc[mf][nf][r]);
      }
}

// ---------------------------------------------------------------------------
extern "C" void kernel_launch(void* const* d_in, const int* in_sizes, int n_in,
                              void* d_out, int out_size, void* d_ws, size_t ws_size,
                              hipStream_t stream) {
  const float* q    = (const float*)d_in[0];
  const float* k    = (const float*)d_in[1];
  const float* w_q  = (const float*)d_in[2];
  const float* w_kv = (const float*)d_in[3];
  const float* w_qd = (const float*)d_in[4];
  const float* w_kd = (const float*)d_in[5];
  const float* w_o  = (const float*)d_in[6];
  const float* temp = (const float*)d_in[7];
  const float* lnqw = (const float*)d_in[8];
  const float* lnqb = (const float*)d_in[9];
  const float* lnkw = (const float*)d_in[10];
  const float* lnkb = (const float*)d_in[11];
  float* out = (float*)d_out;

  char* ws = (char*)d_ws;
  size_t off = 0;
  auto alloc = [&](size_t bytes) -> void* {
    void* p = ws + off;
    off += (bytes + 255) & ~(size_t)255;
    return p;
  };

  u16*   wqp   = (u16*)alloc(384 * 384 * 2);
  float* rwsQ  = (float*)alloc(384 * 4);
  float* biasQ = (float*)alloc(384 * 4);
  u16*   wkvp  = (u16*)alloc(256 * 384 * 2);   // padded to 256 rows
  float* rwsKV = (float*)alloc(256 * 4);
  float* biasKV= (float*)alloc(256 * 4);
  u16*   wop   = (u16*)alloc(384 * 384 * 2);
  u16*   qp    = (u16*)alloc((size_t)NB * CDIM * HW * 2);  // aliased as yt later
  u16*   kvp   = (u16*)alloc((size_t)NB * KVC * HW * 2);
  u16*   qd    = (u16*)alloc((size_t)NB * CDIM * HW * 2);
  u16*   kvd   = (u16*)alloc((size_t)NB * KVC * HW * 2);
  u16*   vt    = (u16*)alloc((size_t)NB * HW * 96 * 2);
  float* spart = (float*)alloc((size_t)4096 * 2304 * 4);
  u16*   ptil  = (u16*)alloc((size_t)NB * CDIM * 96 * 2);
  float* rnq   = (float*)alloc((size_t)NB * 384 * 4);
  float* rnk   = (float*)alloc((size_t)NB * 96 * 4);

  // lifetime alias (sequential stream => safe): qp dead after k4
  u16* yt = qp;

  k0_prep<<<4, 256, 0, stream>>>(w_q, w_kv, w_o, lnqw, lnqb, lnkw, lnkb,
                                 wqp, rwsQ, biasQ, wkvp, rwsKV, biasKV, wop);

  // B fetched exactly once per pixel; pt XCD-swizzled inside the kernel
  gemm_fused<0, 8, 1, 3, 4><<<dim3(256, 1, NB), 512, 0, stream>>>(wqp, q, rwsQ, biasQ, qp, 384);
  gemm_fused<0, 4, 2, 3, 2><<<dim3(256, 1, NB), 512, 0, stream>>>(wkvp, k, rwsKV, biasKV, kvp, 192);

  k4_dw<<<dim3(576, NB), 256, 0, stream>>>(qp, kvp, w_qd, w_kd, qd, kvd, rnq, rnk);

  k5b_vt<<<dim3(64, NB), 256, 0, stream>>>(kvd, vt);

  k6_qk<<<dim3(16, 8, NB), 256, 0, stream>>>(qd, kvd, spart);
  k7_sm<<<dim3(8, NB), 64, 0, stream>>>(spart, temp, rnq, rnk, ptil);

  k8_pv<<<dim3(128, NB), 512, 0, stream>>>(vt, ptil, yt);

  gemm_fused<1, 8, 1, 3, 4><<<dim3(256, 1, NB), 512, 0, stream>>>(wop, yt, nullptr, nullptr, out, 384);
}

// Round 12
// 620.257 us; speedup vs baseline: 2.2124x; 1.0128x over previous
//
#include <hip/hip_runtime.h>
#include <math.h>

// ---------------------------------------------------------------------------
// CrossGroupedQueryAttention on MI355X — round 12
//
// R11 post-mortem: write-coalescing NEUTRAL; traffic byte-ideal but nothing
// busy. The overlooked counter: VGPR_Count=56 — plain launch_bounds(512) made
// the compiler register-minimize, so phase1's 48 loads and phase2's A-loads
// serialize on latency (900cy x 12 per block ~ the 165us floor seen across
// ALL seven GEMM structures R4-R11). Registers, not barriers/segments/XCD,
// were the invariant.
// R12 (structure identical to R11): (1) launch_bounds(512,4) -> 128 VGPR;
// (2) phase1 loads ALL values to a reg array before any use (48-deep MLP,
// one latency); (3) phase2 ping-pong a[2]/bb[2] prefetch (L2 latency under
// MFMA). Abort-check: WRITE_SIZE must stay 98MB (no scratch).
// ---------------------------------------------------------------------------

typedef unsigned short u16;
typedef unsigned int u32;
typedef short s16x8 __attribute__((ext_vector_type(8)));
typedef float f32x4 __attribute__((ext_vector_type(4)));

#define HW 16384
#define NB 8
#define CDIM 384
#define KVC 192

__device__ __forceinline__ float b2f(u16 u) {
  return __uint_as_float(((u32)u) << 16);
}
__device__ __forceinline__ u16 f2b(float f) {
  u32 u = __float_as_uint(f);
  u += 0x7fffu + ((u >> 16) & 1u);   // RNE
  return (u16)(u >> 16);
}
__device__ __forceinline__ u32 pack2(float a, float c) {
  return (u32)f2b(a) | ((u32)f2b(c) << 16);
}

// ---------------------------------------------------------------------------
// k0: fold LN weights into conv weights.  1024 threads.
// ---------------------------------------------------------------------------
__global__ void k0_prep(const float* __restrict__ wq, const float* __restrict__ wkv,
                        const float* __restrict__ wo,
                        const float* __restrict__ lnqw, const float* __restrict__ lnqb,
                        const float* __restrict__ lnkw, const float* __restrict__ lnkb,
                        u16* __restrict__ wqp, float* __restrict__ rwsQ, float* __restrict__ biasQ,
                        u16* __restrict__ wkvp, float* __restrict__ rwsKV, float* __restrict__ biasKV,
                        u16* __restrict__ wop) {
  int r = blockIdx.x * 256 + threadIdx.x;
  if (r < 384) {
    float rs = 0.f, bs = 0.f;
    for (int i = 0; i < 384; ++i) {
      float wp = wq[r * 384 + i] * lnqw[i];
      u16 h = f2b(wp);
      rs += b2f(h);
      bs += wq[r * 384 + i] * lnqb[i];
      wqp[r * 384 + i] = h;
    }
    rwsQ[r] = rs; biasQ[r] = bs;
  } else if (r < 640) {
    int o = r - 384;
    if (o < 192) {
      float rs = 0.f, bs = 0.f;
      for (int i = 0; i < 384; ++i) {
        float wp = wkv[o * 384 + i] * lnkw[i];
        u16 h = f2b(wp);
        rs += b2f(h);
        bs += wkv[o * 384 + i] * lnkb[i];
        wkvp[o * 384 + i] = h;
      }
      rwsKV[o] = rs; biasKV[o] = bs;
    } else {
      for (int i = 0; i < 384; ++i) wkvp[o * 384 + i] = 0;
      rwsKV[o] = 0.f; biasKV[o] = 0.f;
    }
  } else {
    int o = r - 640;
    for (int i = 0; i < 384; ++i) wop[o * 384 + i] = f2b(wo[o * 384 + i]);
  }
}

// ---------------------------------------------------------------------------
// gemm_fused: D[o][p] = sum_k A[o][k]*B[p][k], K=384, tile M x 64px,
// 512 thr (8 waves, WM x WN, wave-tile (MF*16) x (NF*16)).
// Phase 1: batched reg-load of full B panel -> LDS (48KB, swizzled) + stats.
// ONE barrier. Phase 2: 12 K-steps, A direct from L2 with 1-step ping-pong
// prefetch (a[2]/bb[2], statically indexed post-unroll). Epilogue via LDS
// transpose (128B/256B segments). pt XCD-bijective swizzle.
// ---------------------------------------------------------------------------
template <int MODE, int WM, int WN, int MF, int NF>
__global__ __launch_bounds__(512, 4) void gemm_fused(const u16* __restrict__ A,
                                                     const void* __restrict__ Bsrc,
                                                     const float* __restrict__ rowsum,
                                                     const float* __restrict__ bias,
                                                     void* __restrict__ outv, int M) {
  __shared__ __align__(16) char smem[57344];
  u16*   tB    = (u16*)smem;                  // 64 x 384 u16 = 48 KB
  float* sredS = (float*)(smem + 49152);      // [8][64]
  float* sredQ = (float*)(smem + 53248);      // [8][64]
  u16*   chB16 = (u16*)smem;                  // epilogue: [M_TILE][72] u16
  float* chB32 = (float*)smem;                // epilogue: [192][72] f32
  __shared__ float muL[64], sdL[64];

  constexpr int M_TILE = WM * MF * 16;

  const int b = blockIdx.z;
  const int pt = ((blockIdx.x & 7) << 5) | (blockIdx.x >> 3);   // XCD-bijective
  const int tid = threadIdx.x;
  const int w = tid >> 6, l = tid & 63;
  const int wm = (WN == 1) ? w : (w >> 1);
  const int wn = (WN == 1) ? 0 : (w & 1);
  const int lr = l & 15, lg = l >> 4;

  f32x4 acc[MF][NF] = {};

  // ================= Phase 1: stage B panel (batched loads) ================
  if (MODE == 0) {
    const float* Bf = (const float*)Bsrc;
    const size_t fbase = (size_t)b * CDIM * HW + (size_t)pt * 64 + l;  // lane=px
    float v[48];
    // ALL 48 loads issued before any consumer -> 48-deep MLP, one latency
#pragma unroll
    for (int it = 0; it < 12; ++it)
#pragma unroll
      for (int j = 0; j < 4; ++j)
        v[it * 4 + j] = Bf[fbase + (size_t)(it * 32 + w * 4 + j) * HW];

    float s_ = 0.f, q_ = 0.f;
#pragma unroll
    for (int it = 0; it < 12; ++it) {
      float v0 = v[it * 4], v1 = v[it * 4 + 1], v2 = v[it * 4 + 2], v3 = v[it * 4 + 3];
      s_ += (v0 + v1) + (v2 + v3);
      q_ += (v0 * v0 + v1 * v1) + (v2 * v2 + v3 * v3);
      u32 lo = pack2(v0, v1), hi = pack2(v2, v3);
      int cidx = it * 4 + (w >> 1);                 // 16B chunk index (0..47)
      int off = l * 384 + ((cidx ^ (l & 7)) << 3) + (w & 1) * 4;  // u16 units
      *(uint2*)&tB[off] = make_uint2(lo, hi);
    }
    sredS[w * 64 + l] = s_;
    sredQ[w * 64 + l] = q_;
  } else {
    const u16* Bh = (const u16*)Bsrc;
    uint4 v[6];
#pragma unroll
    for (int i = 0; i < 6; ++i) {
      int chunk = tid + i * 512;                    // 0..3071
      int row = chunk / 48, c = chunk % 48;
      v[i] = *(const uint4*)(Bh + ((size_t)(b * HW + pt * 64 + row)) * 384 + c * 8);
    }
#pragma unroll
    for (int i = 0; i < 6; ++i) {
      int chunk = tid + i * 512;
      int row = chunk / 48, c = chunk % 48;
      *(uint4*)&tB[row * 384 + ((c ^ (row & 7)) << 3)] = v[i];
    }
  }
  __syncthreads();

  // LN stats combine (MODE 0)
  if (MODE == 0) {
    if (tid < 64) {
      float s = 0.f, q2 = 0.f;
#pragma unroll
      for (int g = 0; g < 8; ++g) { s += sredS[g * 64 + tid]; q2 += sredQ[g * 64 + tid]; }
      float mn = s * (1.f / 384.f);
      float var = q2 * (1.f / 384.f) - mn * mn;
      muL[tid] = mn;
      sdL[tid] = rsqrtf(var + 1e-5f);
    }
    __syncthreads();
  }

  // ================= Phase 2: MFMA, ping-pong prefetch, no barriers ========
  s16x8 a[2][MF], bb[2][NF];
  {
    // prologue loads for ks=0
#pragma unroll
    for (int mf = 0; mf < MF; ++mf)
      a[0][mf] = *(const s16x8*)(A + (size_t)(wm * (MF * 16) + mf * 16 + lr) * 384 + lg * 8);
#pragma unroll
    for (int nf = 0; nf < NF; ++nf) {
      int row = wn * (NF * 16) + nf * 16 + lr;
      bb[0][nf] = *(const s16x8*)&tB[row * 384 + ((lg ^ (row & 7)) << 3)];
    }
  }
#pragma unroll
  for (int ks = 0; ks < 12; ++ks) {
    const int cur = ks & 1, nxt = cur ^ 1;
    if (ks < 11) {
      const int ko = (ks + 1) * 32 + lg * 8;
      const int cidx = (ks + 1) * 4 + lg;
#pragma unroll
      for (int mf = 0; mf < MF; ++mf)
        a[nxt][mf] = *(const s16x8*)(A + (size_t)(wm * (MF * 16) + mf * 16 + lr) * 384 + ko);
#pragma unroll
      for (int nf = 0; nf < NF; ++nf) {
        int row = wn * (NF * 16) + nf * 16 + lr;
        bb[nxt][nf] = *(const s16x8*)&tB[row * 384 + ((cidx ^ (row & 7)) << 3)];
      }
    }
#pragma unroll
    for (int mf = 0; mf < MF; ++mf)
#pragma unroll
      for (int nf = 0; nf < NF; ++nf)
        acc[mf][nf] = __builtin_amdgcn_mfma_f32_16x16x32_bf16(a[cur][mf], bb[cur][nf], acc[mf][nf], 0, 0, 0);
  }

  // ================= Epilogue: LDS transpose -> coalesced stores ==========
  if (MODE == 0) {
    __syncthreads();                           // tB reads done; reuse as chB16
#pragma unroll
    for (int nf = 0; nf < NF; ++nf) {
      int prow = wn * (NF * 16) + nf * 16 + lr;          // pixel 0..63
      float m_ = muL[prow], s_ = sdL[prow];
#pragma unroll
      for (int mf = 0; mf < MF; ++mf)
#pragma unroll
        for (int r = 0; r < 4; ++r) {
          int orow = wm * (MF * 16) + mf * 16 + lg * 4 + r;
          float v = s_ * (acc[mf][nf][r] - m_ * rowsum[orow]) + bias[orow];
          chB16[orow * 72 + prow] = f2b(v);
        }
    }
    __syncthreads();
    // store: each uint4 = 8px x bf16; instr = 8 rows x 128B segments
    const int total = M_TILE * 8;
    for (int i = tid; i < total; i += 512) {
      int row = i >> 3, c8 = i & 7;
      uint4 v = *(const uint4*)&chB16[row * 72 + c8 * 8];
      *(uint4*)((u16*)outv + ((size_t)(b * M + row)) * HW + pt * 64 + c8 * 8) = v;
    }
  } else {
    // f32 out, 384 rows in 2 chunks of 192 (55 KB each)
#pragma unroll
    for (int cc = 0; cc < 2; ++cc) {
      __syncthreads();                         // protect prev reads / tB
      if ((wm >> 2) == cc) {
#pragma unroll
        for (int nf = 0; nf < NF; ++nf) {
          int prow = wn * (NF * 16) + nf * 16 + lr;
#pragma unroll
          for (int mf = 0; mf < MF; ++mf)
#pragma unroll
            for (int r = 0; r < 4; ++r) {
              int orow_l = (wm & 3) * (MF * 16) + mf * 16 + lg * 4 + r;
              chB32[orow_l * 72 + prow] = acc[mf][nf][r];
            }
        }
      }
      __syncthreads();
      // store: uint4 = 4px f32; instr = 4 rows x 256B segments
      for (int i = tid; i < 192 * 16; i += 512) {
        int row = i >> 4, c4 = i & 15;
        uint4 v = *(const uint4*)&chB32[row * 72 + c4 * 4];
        *(uint4*)((float*)outv + ((size_t)(b * CDIM + cc * 192 + row)) * HW + pt * 64 + c4 * 4) = v;
      }
    }
  }
}

// ---------------------------------------------------------------------------
// k4: depthwise 3x3 (zero pad), LDS-staged plane + fused row l2-norm.
// ---------------------------------------------------------------------------
__global__ __launch_bounds__(256) void k4_dw(const u16* __restrict__ qp, const u16* __restrict__ kvp,
                                             const float* __restrict__ wqdw, const float* __restrict__ wkvdw,
                                             u16* __restrict__ qd, u16* __restrict__ kvd,
                                             float* __restrict__ rnq, float* __restrict__ rnk) {
  __shared__ u16 plane[16384];     // 32 KB
  __shared__ float red[256];

  int c = blockIdx.x, b = blockIdx.y;
  int tid = threadIdx.x;
  const u16* in; u16* outb; const float* wp; int C;
  int isQ = (c < 384), cc = isQ ? c : c - 384;
  if (isQ) { in = qp; outb = qd; wp = wqdw + cc * 9; C = CDIM; }
  else     { in = kvp; outb = kvd; wp = wkvdw + cc * 9; C = KVC; }
  size_t base = ((size_t)(b * C + cc)) * HW;

  float w[9];
#pragma unroll
  for (int j = 0; j < 9; ++j) w[j] = wp[j];

  const uint4* gsrc = (const uint4*)(in + base);
  uint4* lplane = (uint4*)plane;
#pragma unroll
  for (int i = 0; i < 8; ++i) lplane[tid + i * 256] = gsrc[tid + i * 256];
  __syncthreads();

  uint4* gdst = (uint4*)(outb + base);
  float ns = 0.f;
#pragma unroll
  for (int it = 0; it < 8; ++it) {
    int idx = tid + it * 256;
    int y = idx >> 4, ox = idx & 15;
    int x0 = ox * 8;

    float r[3][10];
#pragma unroll
    for (int rr = 0; rr < 3; ++rr) {
      int yy = y + rr - 1;
      if ((unsigned)yy < 128u) {
        int rbase = yy * 128 + x0;
        r[rr][0] = (x0 > 0) ? b2f(plane[rbase - 1]) : 0.f;
        uint4 v = *(const uint4*)&plane[rbase];
        u32 ws[4] = {v.x, v.y, v.z, v.w};
#pragma unroll
        for (int j = 0; j < 4; ++j) {
          r[rr][1 + 2 * j] = b2f((u16)(ws[j] & 0xffff));
          r[rr][2 + 2 * j] = b2f((u16)(ws[j] >> 16));
        }
        r[rr][9] = (x0 < 120) ? b2f(plane[rbase + 8]) : 0.f;
      } else {
#pragma unroll
        for (int j = 0; j < 10; ++j) r[rr][j] = 0.f;
      }
    }

    u32 packed[4];
#pragma unroll
    for (int j = 0; j < 8; ++j) {
      float a = 0.f;
#pragma unroll
      for (int rr = 0; rr < 3; ++rr)
#pragma unroll
        for (int dx = 0; dx < 3; ++dx)
          a += w[rr * 3 + dx] * r[rr][j + dx];
      u16 h = f2b(a);
      float hv = b2f(h);
      ns += hv * hv;
      if (j & 1) packed[j >> 1] |= ((u32)h) << 16; else packed[j >> 1] = (u32)h;
    }
    gdst[idx] = make_uint4(packed[0], packed[1], packed[2], packed[3]);
  }

  red[tid] = ns;
  __syncthreads();
  for (int st = 128; st > 0; st >>= 1) {
    if (tid < st) red[tid] += red[tid + st];
    __syncthreads();
  }
  if (tid == 0) {
    float n = sqrtf(red[0]);
    float inv = 1.f / fmaxf(n, 1e-12f);
    if (isQ) rnq[b * 384 + cc] = inv;
    else if (cc < 96) rnk[b * 96 + cc] = inv;
  }
}

// ---------------------------------------------------------------------------
// k5b: transpose v (kvd rows 96..191) -> vt [b][p][96] bf16. grid (64, 8).
// ---------------------------------------------------------------------------
__global__ void k5b_vt(const u16* __restrict__ kvd, u16* __restrict__ vt) {
  int p = blockIdx.x * 256 + threadIdx.x;
  int b = blockIdx.y;
  size_t sb = ((size_t)(b * KVC + 96)) * HW + p;
  uint4* dv = (uint4*)vt + ((size_t)(b * HW + p)) * 12;
  for (int j8 = 0; j8 < 12; ++j8) {
    u32 w[4];
#pragma unroll
    for (int j = 0; j < 8; ++j) {
      u16 h = kvd[sb + (size_t)(j8 * 8 + j) * HW];
      if (j & 1) w[j >> 1] |= ((u32)h) << 16; else w[j >> 1] = (u32)h;
    }
    dv[j8] = make_uint4(w[0], w[1], w[2], w[3]);
  }
}

// ---------------------------------------------------------------------------
// k6: split-K QK^T partials. grid (16, 8, 8).
// ---------------------------------------------------------------------------
__global__ __launch_bounds__(256) void k6_qk(const u16* __restrict__ qd,
                                             const u16* __restrict__ kvd,
                                             float* __restrict__ spart) {
  int kc = blockIdx.x, h = blockIdx.y, b = blockIdx.z;
  int tid = threadIdx.x;
  int w = tid >> 6, l = tid & 63, lr = l & 15, lg = l >> 4;
  int g = h >> 2;
  int p0 = kc * 1024 + w * 256;

  f32x4 acc[3][3] = {};
  size_t qbase = ((size_t)(b * CDIM + h * 48 + lr)) * HW;
  size_t kbase = ((size_t)(b * KVC + g * 48 + lr)) * HW;

  for (int ks = 0; ks < 8; ++ks) {
    int pp = p0 + ks * 32 + lg * 8;
    s16x8 a[3], bb[3];
#pragma unroll
    for (int mi = 0; mi < 3; ++mi) a[mi] = *(const s16x8*)(qd + qbase + (size_t)mi * 16 * HW + pp);
#pragma unroll
    for (int ni = 0; ni < 3; ++ni) bb[ni] = *(const s16x8*)(kvd + kbase + (size_t)ni * 16 * HW + pp);
#pragma unroll
    for (int mi = 0; mi < 3; ++mi)
#pragma unroll
      for (int ni = 0; ni < 3; ++ni)
        acc[mi][ni] = __builtin_amdgcn_mfma_f32_16x16x32_bf16(a[mi], bb[ni], acc[mi][ni], 0, 0, 0);
  }

  size_t sb = ((size_t)((((b * 8 + h) * 16) + kc) * 4 + w)) * 2304;
#pragma unroll
  for (int mi = 0; mi < 3; ++mi)
#pragma unroll
    for (int ni = 0; ni < 3; ++ni)
#pragma unroll
      for (int r = 0; r < 4; ++r) {
        int c = mi * 16 + lg * 4 + r, d = ni * 16 + lr;
        spart[sb + c * 48 + d] = acc[mi][ni][r];
      }
}

// ---------------------------------------------------------------------------
// k7: reduce partials + scale + softmax -> P~ [b][384][96] bf16.
// ---------------------------------------------------------------------------
__global__ void k7_sm(const float* __restrict__ spart, const float* __restrict__ temp,
                      const float* __restrict__ rnq, const float* __restrict__ rnk,
                      u16* __restrict__ ptil) {
  int h = blockIdx.x, b = blockIdx.y, tid = threadIdx.x;
  int g = h >> 2;
  __shared__ float S[2304];
  size_t base = ((size_t)((b * 8 + h) * 64)) * 2304;
  for (int e = tid; e < 2304; e += 64) {
    float s = 0.f;
    for (int j = 0; j < 64; ++j) s += spart[base + (size_t)j * 2304 + e];
    S[e] = s;
  }
  __syncthreads();
  if (tid < 48) {
    int c = tid;
    float sq = temp[h] * rnq[b * 384 + h * 48 + c];
    float mx = -1e30f;
    for (int d = 0; d < 48; ++d) {
      float v = S[c * 48 + d] * sq * rnk[b * 96 + g * 48 + d];
      mx = fmaxf(mx, v);
    }
    float sum = 0.f;
    for (int d = 0; d < 48; ++d) {
      float v = S[c * 48 + d] * sq * rnk[b * 96 + g * 48 + d];
      sum += __expf(v - mx);
    }
    float inv = 1.f / sum;
    u16* row = ptil + ((size_t)(b * 384 + h * 48 + c)) * 96;
    for (int dk = 0; dk < 96; ++dk) {
      int d = dk - g * 48;
      float pv = 0.f;
      if (d >= 0 && d < 48) {
        float v = S[c * 48 + d] * sq * rnk[b * 96 + g * 48 + d];
        pv = __expf(v - mx) * inv;
      }
      row[dk] = f2b(pv);
    }
  }
}

// ---------------------------------------------------------------------------
// k8: Yt[p][c] = sum_dk vt[p][dk] * P~[c][dk].  grid (128, 8), 512 thr.
// ---------------------------------------------------------------------------
__global__ __launch_bounds__(512) void k8_pv(const u16* __restrict__ vt,
                                             const u16* __restrict__ ptil,
                                             u16* __restrict__ yt) {
  int ptb = blockIdx.x, b = blockIdx.y;
  int tid = threadIdx.x;
  int w = tid >> 6, l = tid & 63, lr = l & 15, lg = l >> 4;
  int wm = w >> 2, wn = w & 3;

  f32x4 acc[4][6] = {};
  size_t arow0 = ((size_t)(b * HW + ptb * 128 + wm * 64 + lr)) * 96;
  size_t brow0 = ((size_t)(b * CDIM + wn * 96 + lr)) * 96;

  for (int ks = 0; ks < 3; ++ks) {
    int ko = ks * 32 + lg * 8;
    s16x8 a[4], bb[6];
#pragma unroll
    for (int mf = 0; mf < 4; ++mf) a[mf] = *(const s16x8*)(vt + arow0 + (size_t)mf * 16 * 96 + ko);
#pragma unroll
    for (int nf = 0; nf < 6; ++nf) bb[nf] = *(const s16x8*)(ptil + brow0 + (size_t)nf * 16 * 96 + ko);
#pragma unroll
    for (int mf = 0; mf < 4; ++mf)
#pragma unroll
      for (int nf = 0; nf < 6; ++nf)
        acc[mf][nf] = __builtin_amdgcn_mfma_f32_16x16x32_bf16(a[mf], bb[nf], acc[mf][nf], 0, 0, 0);
  }

#pragma unroll
  for (int mf = 0; mf < 4; ++mf)
#pragma unroll
    for (int nf = 0; nf < 6; ++nf)
#pragma unroll
      for (int r = 0; r < 4; ++r) {
        int p = ptb * 128 + wm * 64 + mf * 16 + lg * 4 + r;
        int c = wn * 96 + nf * 16 + lr;
        yt[((size_t)(b * HW + p)) * 384 + c] = f2b(acc[mf][nf][r]);
      }
}

// ---------------------------------------------------------------------------
extern "C" void kernel_launch(void* const* d_in, const int* in_sizes, int n_in,
                              void* d_out, int out_size, void* d_ws, size_t ws_size,
                              hipStream_t stream) {
  const float* q    = (const float*)d_in[0];
  const float* k    = (const float*)d_in[1];
  const float* w_q  = (const float*)d_in[2];
  const float* w_kv = (const float*)d_in[3];
  const float* w_qd = (const float*)d_in[4];
  const float* w_kd = (const float*)d_in[5];
  const float* w_o  = (const float*)d_in[6];
  const float* temp = (const float*)d_in[7];
  const float* lnqw = (const float*)d_in[8];
  const float* lnqb = (const float*)d_in[9];
  const float* lnkw = (const float*)d_in[10];
  const float* lnkb = (const float*)d_in[11];
  float* out = (float*)d_out;

  char* ws = (char*)d_ws;
  size_t off = 0;
  auto alloc = [&](size_t bytes) -> void* {
    void* p = ws + off;
    off += (bytes + 255) & ~(size_t)255;
    return p;
  };

  u16*   wqp   = (u16*)alloc(384 * 384 * 2);
  float* rwsQ  = (float*)alloc(384 * 4);
  float* biasQ = (float*)alloc(384 * 4);
  u16*   wkvp  = (u16*)alloc(256 * 384 * 2);   // padded to 256 rows
  float* rwsKV = (float*)alloc(256 * 4);
  float* biasKV= (float*)alloc(256 * 4);
  u16*   wop   = (u16*)alloc(384 * 384 * 2);
  u16*   qp    = (u16*)alloc((size_t)NB * CDIM * HW * 2);  // aliased as yt later
  u16*   kvp   = (u16*)alloc((size_t)NB * KVC * HW * 2);
  u16*   qd    = (u16*)alloc((size_t)NB * CDIM * HW * 2);
  u16*   kvd   = (u16*)alloc((size_t)NB * KVC * HW * 2);
  u16*   vt    = (u16*)alloc((size_t)NB * HW * 96 * 2);
  float* spart = (float*)alloc((size_t)4096 * 2304 * 4);
  u16*   ptil  = (u16*)alloc((size_t)NB * CDIM * 96 * 2);
  float* rnq   = (float*)alloc((size_t)NB * 384 * 4);
  float* rnk   = (float*)alloc((size_t)NB * 96 * 4);

  // lifetime alias (sequential stream => safe): qp dead after k4
  u16* yt = qp;

  k0_prep<<<4, 256, 0, stream>>>(w_q, w_kv, w_o, lnqw, lnqb, lnkw, lnkb,
                                 wqp, rwsQ, biasQ, wkvp, rwsKV, biasKV, wop);

  // B fetched exactly once per pixel; pt XCD-swizzled inside the kernel
  gemm_fused<0, 8, 1, 3, 4><<<dim3(256, 1, NB), 512, 0, stream>>>(wqp, q, rwsQ, biasQ, qp, 384);
  gemm_fused<0, 4, 2, 3, 2><<<dim3(256, 1, NB), 512, 0, stream>>>(wkvp, k, rwsKV, biasKV, kvp, 192);

  k4_dw<<<dim3(576, NB), 256, 0, stream>>>(qp, kvp, w_qd, w_kd, qd, kvd, rnq, rnk);

  k5b_vt<<<dim3(64, NB), 256, 0, stream>>>(kvd, vt);

  k6_qk<<<dim3(16, 8, NB), 256, 0, stream>>>(qd, kvd, spart);
  k7_sm<<<dim3(8, NB), 64, 0, stream>>>(spart, temp, rnq, rnk, ptil);

  k8_pv<<<dim3(128, NB), 512, 0, stream>>>(vt, ptil, yt);

  gemm_fused<1, 8, 1, 3, 4><<<dim3(256, 1, NB), 512, 0, stream>>>(wop, yt, nullptr, nullptr, out, 384);
}